// Round 1
// baseline (3581.424 us; speedup 1.0000x reference)
//
#include <hip/hip_runtime.h>
#include <hip/hip_bf16.h>
#include <math.h>

#define Bb 2
#define Ss 2048
#define Ee 1024
#define Hh 16
#define Oo 32
#define Cc 2
#define EPSf 1e-5f

// ---------------- LayerNorm: one block (256 thr) per row of E=1024 ----------------
__global__ __launch_bounds__(256) void ln_kernel(const float* __restrict__ x,
                                                 const float* __restrict__ g,
                                                 float* __restrict__ out) {
    __shared__ float red[8];
    int row = blockIdx.x;                       // 0..B*S-1
    const float4* xr = (const float4*)(x + (size_t)row * Ee);
    float4 v = xr[threadIdx.x];
    float s = v.x + v.y + v.z + v.w;
#pragma unroll
    for (int off = 32; off > 0; off >>= 1) s += __shfl_xor(s, off);
    int wave = threadIdx.x >> 6, lane = threadIdx.x & 63;
    if (!lane) red[wave] = s;
    __syncthreads();
    float mu = (red[0] + red[1] + red[2] + red[3]) * (1.0f / Ee);
    float dx = v.x - mu, dy = v.y - mu, dz = v.z - mu, dw = v.w - mu;
    float sq = dx * dx + dy * dy + dz * dz + dw * dw;
#pragma unroll
    for (int off = 32; off > 0; off >>= 1) sq += __shfl_xor(sq, off);
    if (!lane) red[wave + 4] = sq;
    __syncthreads();
    float var = (red[4] + red[5] + red[6] + red[7]) * (1.0f / Ee);
    float rs = rsqrtf(var + EPSf);
    float4 gv = ((const float4*)g)[threadIdx.x];
    float4 o;
    o.x = dx * rs * gv.x;
    o.y = dy * rs * gv.y;
    o.z = dz * rs * gv.z;
    o.w = dw * rs * gv.w;
    ((float4*)(out + (size_t)row * Ee))[threadIdx.x] = o;
}

// ---------------- Sequential rank-2 scan: one 1024-thread block per (b,head) ----------------
// P_t = P_{t-1} (I + A_t Wup^T)  ->  P += (P A_t) Wup^T     (A_t = hh[b,t,head] as [O,C])
// down_t[o][c] = sum_q P[o][q] * Wdn[c][q]
// states for b==B-1 are streamed to d_out's state section.
__global__ __launch_bounds__(1024) void scan_kernel(const float* __restrict__ h,
                                                    const float* __restrict__ Wup,
                                                    const float* __restrict__ Wdn,
                                                    float* __restrict__ down,
                                                    float* __restrict__ state_out) {
    const int TS = 64;                           // staged steps; LDS = 64*64*4 = 16KB
    __shared__ float As[TS][64];
    int chain = blockIdx.x;                      // 0..31
    int b = chain >> 4;
    int head = chain & 15;
    int tid = threadIdx.x;
    int o = tid >> 5, q = tid & 31;

    float wq0 = Wup[q * Cc + 0], wq1 = Wup[q * Cc + 1];
    float wd0 = Wdn[0 * Oo + q], wd1 = Wdn[1 * Oo + q];
    float p = (o == q) ? 1.0f : 0.0f;

    const float* hbase = h + (size_t)b * Ss * Ee + head * (Oo * Cc);
    float* dbase = down + (size_t)b * Ss * Ee + head * (Oo * Cc);

    for (int t0 = 0; t0 < Ss; t0 += TS) {
        __syncthreads();                         // protect As from previous reads
        // cooperative stage: TS*64 floats, 1024 threads -> 4 each
#pragma unroll
        for (int i = tid; i < TS * 64; i += 1024) {
            int st = i >> 6;
            int j = i & 63;
            As[st][j] = hbase[(size_t)(t0 + st) * Ee + j];
        }
        __syncthreads();
        for (int st = 0; st < TS; ++st) {
            int t = t0 + st;
            float a0 = As[st][q * 2 + 0];
            float a1 = As[st][q * 2 + 1];
            float y0 = p * a0, y1 = p * a1;
#pragma unroll
            for (int off = 16; off > 0; off >>= 1) {
                y0 += __shfl_xor(y0, off, 32);
                y1 += __shfl_xor(y1, off, 32);
            }
            p += y0 * wq0 + y1 * wq1;
            float d0 = p * wd0, d1 = p * wd1;
#pragma unroll
            for (int off = 16; off > 0; off >>= 1) {
                d0 += __shfl_xor(d0, off, 32);
                d1 += __shfl_xor(d1, off, 32);
            }
            if (q < 2) {
                dbase[(size_t)t * Ee + o * 2 + q] = (q == 0) ? d0 : d1;
            }
            if (b == Bb - 1) {
                state_out[(((size_t)t * Hh + head) * Oo + o) * Oo + q] = p;
            }
        }
    }
}

// ---------------- fp32 tiled GEMM: C[M,N] = A[M,K] @ W[N,K]^T  (+ epilogue) ----------------
template <bool GELU, bool RESID>
__global__ __launch_bounds__(256) void gemm_kernel(const float* __restrict__ A,
                                                   const float* __restrict__ W,
                                                   const float* __restrict__ res,
                                                   float* __restrict__ Cmat,
                                                   int M, int N, int K) {
    __shared__ float As[16][65];
    __shared__ float Bs[16][65];
    int bm = blockIdx.y, bn = blockIdx.x;
    int tid = threadIdx.x;
    int tx = tid & 15, ty = tid >> 4;
    int row4 = tid >> 2;                         // 0..63
    int kq = (tid & 3) << 2;                     // 0,4,8,12
    const float* Arow = A + (size_t)(bm * 64 + row4) * K;
    const float* Wrow = W + (size_t)(bn * 64 + row4) * K;
    float acc[4][4] = {{0.f}};
    for (int k0 = 0; k0 < K; k0 += 16) {
        float4 av = *(const float4*)(Arow + k0 + kq);
        float4 bv = *(const float4*)(Wrow + k0 + kq);
        __syncthreads();
        As[kq + 0][row4] = av.x; As[kq + 1][row4] = av.y;
        As[kq + 2][row4] = av.z; As[kq + 3][row4] = av.w;
        Bs[kq + 0][row4] = bv.x; Bs[kq + 1][row4] = bv.y;
        Bs[kq + 2][row4] = bv.z; Bs[kq + 3][row4] = bv.w;
        __syncthreads();
#pragma unroll
        for (int k = 0; k < 16; ++k) {
            float a0 = As[k][ty * 4 + 0], a1 = As[k][ty * 4 + 1];
            float a2 = As[k][ty * 4 + 2], a3 = As[k][ty * 4 + 3];
            float b0 = Bs[k][tx * 4 + 0], b1 = Bs[k][tx * 4 + 1];
            float b2 = Bs[k][tx * 4 + 2], b3 = Bs[k][tx * 4 + 3];
            acc[0][0] += a0 * b0; acc[0][1] += a0 * b1; acc[0][2] += a0 * b2; acc[0][3] += a0 * b3;
            acc[1][0] += a1 * b0; acc[1][1] += a1 * b1; acc[1][2] += a1 * b2; acc[1][3] += a1 * b3;
            acc[2][0] += a2 * b0; acc[2][1] += a2 * b1; acc[2][2] += a2 * b2; acc[2][3] += a2 * b3;
            acc[3][0] += a3 * b0; acc[3][1] += a3 * b1; acc[3][2] += a3 * b2; acc[3][3] += a3 * b3;
        }
    }
#pragma unroll
    for (int i = 0; i < 4; ++i) {
#pragma unroll
        for (int j = 0; j < 4; ++j) {
            int m = bm * 64 + ty * 4 + i;
            int n = bn * 64 + tx * 4 + j;
            float v = acc[i][j];
            if (GELU) v = 0.5f * v * (1.0f + erff(v * 0.70710678118654752f));
            if (RESID) v += res[(size_t)m * N + n];
            Cmat[(size_t)m * N + n] = v;
        }
    }
}

extern "C" void kernel_launch(void* const* d_in, const int* in_sizes, int n_in,
                              void* d_out, int out_size, void* d_ws, size_t ws_size,
                              hipStream_t stream) {
    const float* act    = (const float*)d_in[0];  // [B,S,E]
    const float* W_up   = (const float*)d_in[1];  // [O,C]
    const float* W_down = (const float*)d_in[2];  // [C,O]
    const float* W_mru  = (const float*)d_in[3];  // [E,E]
    const float* g_ln1  = (const float*)d_in[4];  // [E]
    const float* g_ln2  = (const float*)d_in[5];  // [E]
    const float* W_mlp1 = (const float*)d_in[6];  // [4E,E]
    const float* W_mlp2 = (const float*)d_in[7];  // [E,4E]

    float* out_x     = (float*)d_out;                          // [B,S,E] = 4,194,304
    float* out_state = (float*)d_out + (size_t)Bb * Ss * Ee;   // [S,H,O,O]

    float* wsf  = (float*)d_ws;
    float* h    = wsf;                                // 16 MB  [B,S,E]
    float* down = wsf + (size_t)4 * 1024 * 1024;      // 16 MB  [B,S,E]
    float* t1   = wsf + (size_t)8 * 1024 * 1024;      // 64 MB  [B*S, 4E]
    float* y    = h;                                  // reuse (h dead after scan)

    const int MT = Bb * Ss;      // 4096 rows

    // 1. LN1
    ln_kernel<<<MT, 256, 0, stream>>>(act, g_ln1, h);
    // 2. scan (+ state output for b=1, + down projection)
    scan_kernel<<<32, 1024, 0, stream>>>(h, W_up, W_down, down, out_state);
    // 3. mru GEMM + residual:  x1 = act + down @ W_mru^T   -> out_x
    {
        dim3 grid(Ee / 64, MT / 64);
        gemm_kernel<false, true><<<grid, 256, 0, stream>>>(down, W_mru, act, out_x, MT, Ee, Ee);
    }
    // 4. LN2
    ln_kernel<<<MT, 256, 0, stream>>>(out_x, g_ln2, y);
    // 5. MLP up + gelu: t1 = gelu(y @ W_mlp1^T)
    {
        dim3 grid(4 * Ee / 64, MT / 64);
        gemm_kernel<true, false><<<grid, 256, 0, stream>>>(y, W_mlp1, nullptr, t1, MT, 4 * Ee, Ee);
    }
    // 6. MLP down + residual: out_x = x1 + t1 @ W_mlp2^T   (in-place residual: safe, 1:1 thread->elem)
    {
        dim3 grid(Ee / 64, MT / 64);
        gemm_kernel<false, true><<<grid, 256, 0, stream>>>(t1, W_mlp2, out_x, out_x, MT, Ee, 4 * Ee);
    }
}

// Round 2
// 1747.469 us; speedup vs baseline: 2.0495x; 2.0495x over previous
//
#include <hip/hip_runtime.h>
#include <hip/hip_bf16.h>
#include <math.h>

#define Bb 2
#define Ss 2048
#define Ee 1024
#define Hh 16
#define Oo 32
#define Cc 2
#define EPSf 1e-5f
#define NSEG 64        // segments per chain
#define SEGL 32        // steps per segment
#define NGRP 8         // groups of segments per chain
#define GRPL 8         // segments per group

// ---------------- LayerNorm: one block (256 thr) per row of E=1024 ----------------
__global__ __launch_bounds__(256) void ln_kernel(const float* __restrict__ x,
                                                 const float* __restrict__ g,
                                                 float* __restrict__ out) {
    __shared__ float red[8];
    int row = blockIdx.x;
    const float4* xr = (const float4*)(x + (size_t)row * Ee);
    float4 v = xr[threadIdx.x];
    float s = v.x + v.y + v.z + v.w;
#pragma unroll
    for (int off = 32; off > 0; off >>= 1) s += __shfl_xor(s, off);
    int wave = threadIdx.x >> 6, lane = threadIdx.x & 63;
    if (!lane) red[wave] = s;
    __syncthreads();
    float mu = (red[0] + red[1] + red[2] + red[3]) * (1.0f / Ee);
    float dx = v.x - mu, dy = v.y - mu, dz = v.z - mu, dw = v.w - mu;
    float sq = dx * dx + dy * dy + dz * dz + dw * dw;
#pragma unroll
    for (int off = 32; off > 0; off >>= 1) sq += __shfl_xor(sq, off);
    if (!lane) red[wave + 4] = sq;
    __syncthreads();
    float var = (red[4] + red[5] + red[6] + red[7]) * (1.0f / Ee);
    float rs = rsqrtf(var + EPSf);
    float4 gv = ((const float4*)g)[threadIdx.x];
    float4 o;
    o.x = dx * rs * gv.x;
    o.y = dy * rs * gv.y;
    o.z = dz * rs * gv.z;
    o.w = dw * rs * gv.w;
    ((float4*)(out + (size_t)row * Ee))[threadIdx.x] = o;
}

// ======================= Segmented scan =======================
// M_t = I + A_t Wup^T (A_t = hh[b,t,head] as [32,2]).  P_t = P_{t-1} @ M_t.
// Lane layout: lane&31 = row o; lanes 32-63 duplicate (no cross-lane ops at all).
// Pass 1: per-segment totals T_g (seed I, 32 rank-2 steps).
// Pass 2a: per group of 8 segments: exclusive prefixes E_{k,i}, group total U_k.
// Pass 2b: per chain: exclusive group prefixes W_k.
// Pass 3: seed = W_k @ E_{k,i}; replay 32 steps emitting down (+ states for b=1).

__device__ __forceinline__ void rank2_step(const float* __restrict__ ap,
                                           const float* __restrict__ wq,
                                           float p[32], float& y0o, float& y1o) {
    float a[64];
#pragma unroll
    for (int j = 0; j < 16; ++j) ((float4*)a)[j] = ((const float4*)ap)[j];
    float s0 = 0.f, s1 = 0.f, s2 = 0.f, s3 = 0.f;
    float u0 = 0.f, u1 = 0.f, u2 = 0.f, u3 = 0.f;
#pragma unroll
    for (int q = 0; q < 32; q += 4) {
        s0 = fmaf(p[q + 0], a[2 * q + 0], s0);
        s1 = fmaf(p[q + 1], a[2 * q + 2], s1);
        s2 = fmaf(p[q + 2], a[2 * q + 4], s2);
        s3 = fmaf(p[q + 3], a[2 * q + 6], s3);
        u0 = fmaf(p[q + 0], a[2 * q + 1], u0);
        u1 = fmaf(p[q + 1], a[2 * q + 3], u1);
        u2 = fmaf(p[q + 2], a[2 * q + 5], u2);
        u3 = fmaf(p[q + 3], a[2 * q + 7], u3);
    }
    float y0 = (s0 + s1) + (s2 + s3);
    float y1 = (u0 + u1) + (u2 + u3);
#pragma unroll
    for (int q = 0; q < 32; ++q) p[q] = fmaf(y0, wq[2 * q], fmaf(y1, wq[2 * q + 1], p[q]));
    y0o = y0; y1o = y1;
}

// e_row (per-lane row o of E) <- e_row @ T   (T rows are wave-uniform global loads)
__device__ __forceinline__ void row_matmul(float e[32], const float* __restrict__ T) {
    float r[32];
#pragma unroll
    for (int q = 0; q < 32; ++q) r[q] = 0.f;
#pragma unroll
    for (int kk = 0; kk < 32; ++kk) {
        float ekk = e[kk];
        const float4* tr = (const float4*)(T + kk * 32);
#pragma unroll
        for (int j = 0; j < 8; ++j) {
            float4 tv = tr[j];
            r[4 * j + 0] = fmaf(ekk, tv.x, r[4 * j + 0]);
            r[4 * j + 1] = fmaf(ekk, tv.y, r[4 * j + 1]);
            r[4 * j + 2] = fmaf(ekk, tv.z, r[4 * j + 2]);
            r[4 * j + 3] = fmaf(ekk, tv.w, r[4 * j + 3]);
        }
    }
#pragma unroll
    for (int q = 0; q < 32; ++q) e[q] = r[q];
}

__global__ __launch_bounds__(256) void scan_pass1(const float* __restrict__ h,
                                                  const float* __restrict__ Wup,
                                                  float* __restrict__ Ttot) {
    int wv = __builtin_amdgcn_readfirstlane((int)(threadIdx.x >> 6));
    int lane = threadIdx.x & 63;
    int o = lane & 31;
    int seg = blockIdx.x * 4 + wv;            // 0..2047
    int chain = seg >> 6;
    int g = seg & 63;
    int b = chain >> 4, head = chain & 15;

    float wq[64];
#pragma unroll
    for (int j = 0; j < 16; ++j) ((float4*)wq)[j] = ((const float4*)Wup)[j];

    float p[32];
#pragma unroll
    for (int q = 0; q < 32; ++q) p[q] = (q == o) ? 1.0f : 0.0f;

    const float* hb = h + ((size_t)b * Ss + (size_t)g * SEGL) * Ee + head * 64;
    for (int st = 0; st < SEGL; ++st) {
        float y0, y1;
        rank2_step(hb + (size_t)st * Ee, wq, p, y0, y1);
    }
    if (lane < 32) {
        float* tb = Ttot + ((size_t)chain * NSEG + g) * 1024 + o * 32;
#pragma unroll
        for (int j = 0; j < 8; ++j)
            ((float4*)tb)[j] = make_float4(p[4 * j], p[4 * j + 1], p[4 * j + 2], p[4 * j + 3]);
    }
}

__global__ __launch_bounds__(64) void scan_pass2a(const float* __restrict__ Ttot,
                                                  float* __restrict__ Eexc,
                                                  float* __restrict__ Utot) {
    int lane = threadIdx.x & 63;
    int o = lane & 31;
    int grp = blockIdx.x;                     // chain*8 + k
    int chain = grp >> 3, k = grp & 7;
    float e[32];
#pragma unroll
    for (int q = 0; q < 32; ++q) e[q] = (q == o) ? 1.0f : 0.0f;
    for (int i = 0; i < GRPL; ++i) {
        int g = k * GRPL + i;
        if (lane < 32) {
            float* eb = Eexc + ((size_t)chain * NSEG + g) * 1024 + o * 32;
#pragma unroll
            for (int j = 0; j < 8; ++j)
                ((float4*)eb)[j] = make_float4(e[4 * j], e[4 * j + 1], e[4 * j + 2], e[4 * j + 3]);
        }
        row_matmul(e, Ttot + ((size_t)chain * NSEG + g) * 1024);
    }
    if (lane < 32) {
        float* ub = Utot + ((size_t)chain * NGRP + k) * 1024 + o * 32;
#pragma unroll
        for (int j = 0; j < 8; ++j)
            ((float4*)ub)[j] = make_float4(e[4 * j], e[4 * j + 1], e[4 * j + 2], e[4 * j + 3]);
    }
}

__global__ __launch_bounds__(64) void scan_pass2b(const float* __restrict__ Utot,
                                                  float* __restrict__ Wkp) {
    int lane = threadIdx.x & 63;
    int o = lane & 31;
    int chain = blockIdx.x;                   // 0..31
    float w[32];
#pragma unroll
    for (int q = 0; q < 32; ++q) w[q] = (q == o) ? 1.0f : 0.0f;
    for (int k = 0; k < NGRP; ++k) {
        if (lane < 32) {
            float* wb = Wkp + ((size_t)chain * NGRP + k) * 1024 + o * 32;
#pragma unroll
            for (int j = 0; j < 8; ++j)
                ((float4*)wb)[j] = make_float4(w[4 * j], w[4 * j + 1], w[4 * j + 2], w[4 * j + 3]);
        }
        row_matmul(w, Utot + ((size_t)chain * NGRP + k) * 1024);
    }
}

__global__ __launch_bounds__(256) void scan_pass3(const float* __restrict__ h,
                                                  const float* __restrict__ Wup,
                                                  const float* __restrict__ Wdn,
                                                  const float* __restrict__ Eexc,
                                                  const float* __restrict__ Wkp,
                                                  float* __restrict__ down,
                                                  float* __restrict__ state_out) {
    int wv = __builtin_amdgcn_readfirstlane((int)(threadIdx.x >> 6));
    int lane = threadIdx.x & 63;
    int o = lane & 31;
    int seg = blockIdx.x * 4 + wv;
    int chain = seg >> 6;
    int g = seg & 63;
    int b = chain >> 4, head = chain & 15;
    int k = g >> 3;

    float wq[64];
#pragma unroll
    for (int j = 0; j < 16; ++j) ((float4*)wq)[j] = ((const float4*)Wup)[j];
    float wd[64];
#pragma unroll
    for (int j = 0; j < 16; ++j) ((float4*)wd)[j] = ((const float4*)Wdn)[j];

    // G[cc][c] = sum_q Wup[q][cc] * Wdn[c][q]
    float G00 = 0.f, G01 = 0.f, G10 = 0.f, G11 = 0.f;
#pragma unroll
    for (int q = 0; q < 32; ++q) {
        G00 = fmaf(wq[2 * q + 0], wd[q], G00);
        G01 = fmaf(wq[2 * q + 0], wd[32 + q], G01);
        G10 = fmaf(wq[2 * q + 1], wd[q], G10);
        G11 = fmaf(wq[2 * q + 1], wd[32 + q], G11);
    }

    // seed P row o = sum_kk Wk[o][kk] * E[kk][:]
    float wrow[32];
    const float* wb = Wkp + ((size_t)chain * NGRP + k) * 1024 + o * 32;
#pragma unroll
    for (int j = 0; j < 8; ++j) ((float4*)wrow)[j] = ((const float4*)wb)[j];
    const float* Eb = Eexc + ((size_t)chain * NSEG + g) * 1024;
    float p[32];
#pragma unroll
    for (int q = 0; q < 32; ++q) p[q] = 0.f;
#pragma unroll
    for (int kk = 0; kk < 32; ++kk) {
        float wkk = wrow[kk];
        const float4* er = (const float4*)(Eb + kk * 32);
#pragma unroll
        for (int j = 0; j < 8; ++j) {
            float4 ev = er[j];
            p[4 * j + 0] = fmaf(wkk, ev.x, p[4 * j + 0]);
            p[4 * j + 1] = fmaf(wkk, ev.y, p[4 * j + 1]);
            p[4 * j + 2] = fmaf(wkk, ev.z, p[4 * j + 2]);
            p[4 * j + 3] = fmaf(wkk, ev.w, p[4 * j + 3]);
        }
    }

    // down accumulator seeded from P
    float d0 = 0.f, d1 = 0.f;
#pragma unroll
    for (int q = 0; q < 32; ++q) {
        d0 = fmaf(p[q], wd[q], d0);
        d1 = fmaf(p[q], wd[32 + q], d1);
    }

    const float* hb = h + ((size_t)b * Ss + (size_t)g * SEGL) * Ee + head * 64;
    float* db = down + ((size_t)b * Ss + (size_t)g * SEGL) * Ee + head * 64 + o * 2;
    float* sb = state_out + ((size_t)g * SEGL * Hh + head) * 1024 + o * 32;

    for (int st = 0; st < SEGL; ++st) {
        float y0, y1;
        rank2_step(hb + (size_t)st * Ee, wq, p, y0, y1);
        d0 = fmaf(y0, G00, fmaf(y1, G10, d0));
        d1 = fmaf(y0, G01, fmaf(y1, G11, d1));
        if (lane < 32) {
            *(float2*)(db + (size_t)st * Ee) = make_float2(d0, d1);
            if (b == Bb - 1) {
                float* sp = sb + (size_t)st * (Hh * 1024);
#pragma unroll
                for (int j = 0; j < 8; ++j)
                    ((float4*)sp)[j] = make_float4(p[4 * j], p[4 * j + 1], p[4 * j + 2], p[4 * j + 3]);
            }
        }
    }
}

// ---------------- fp32 tiled GEMM: C[M,N] = A[M,K] @ W[N,K]^T  (+ epilogue) ----------------
template <bool GELU, bool RESID>
__global__ __launch_bounds__(256) void gemm_kernel(const float* __restrict__ A,
                                                   const float* __restrict__ W,
                                                   const float* __restrict__ res,
                                                   float* __restrict__ Cmat,
                                                   int M, int N, int K) {
    __shared__ float As[16][65];
    __shared__ float Bs[16][65];
    int bm = blockIdx.y, bn = blockIdx.x;
    int tid = threadIdx.x;
    int tx = tid & 15, ty = tid >> 4;
    int row4 = tid >> 2;
    int kq = (tid & 3) << 2;
    const float* Arow = A + (size_t)(bm * 64 + row4) * K;
    const float* Wrow = W + (size_t)(bn * 64 + row4) * K;
    float acc[4][4] = {{0.f}};
    for (int k0 = 0; k0 < K; k0 += 16) {
        float4 av = *(const float4*)(Arow + k0 + kq);
        float4 bv = *(const float4*)(Wrow + k0 + kq);
        __syncthreads();
        As[kq + 0][row4] = av.x; As[kq + 1][row4] = av.y;
        As[kq + 2][row4] = av.z; As[kq + 3][row4] = av.w;
        Bs[kq + 0][row4] = bv.x; Bs[kq + 1][row4] = bv.y;
        Bs[kq + 2][row4] = bv.z; Bs[kq + 3][row4] = bv.w;
        __syncthreads();
#pragma unroll
        for (int k = 0; k < 16; ++k) {
            float a0 = As[k][ty * 4 + 0], a1 = As[k][ty * 4 + 1];
            float a2 = As[k][ty * 4 + 2], a3 = As[k][ty * 4 + 3];
            float b0 = Bs[k][tx * 4 + 0], b1 = Bs[k][tx * 4 + 1];
            float b2 = Bs[k][tx * 4 + 2], b3 = Bs[k][tx * 4 + 3];
            acc[0][0] += a0 * b0; acc[0][1] += a0 * b1; acc[0][2] += a0 * b2; acc[0][3] += a0 * b3;
            acc[1][0] += a1 * b0; acc[1][1] += a1 * b1; acc[1][2] += a1 * b2; acc[1][3] += a1 * b3;
            acc[2][0] += a2 * b0; acc[2][1] += a2 * b1; acc[2][2] += a2 * b2; acc[2][3] += a2 * b3;
            acc[3][0] += a3 * b0; acc[3][1] += a3 * b1; acc[3][2] += a3 * b2; acc[3][3] += a3 * b3;
        }
    }
#pragma unroll
    for (int i = 0; i < 4; ++i) {
#pragma unroll
        for (int j = 0; j < 4; ++j) {
            int m = bm * 64 + ty * 4 + i;
            int n = bn * 64 + tx * 4 + j;
            float v = acc[i][j];
            if (GELU) v = 0.5f * v * (1.0f + erff(v * 0.70710678118654752f));
            if (RESID) v += res[(size_t)m * N + n];
            Cmat[(size_t)m * N + n] = v;
        }
    }
}

extern "C" void kernel_launch(void* const* d_in, const int* in_sizes, int n_in,
                              void* d_out, int out_size, void* d_ws, size_t ws_size,
                              hipStream_t stream) {
    const float* act    = (const float*)d_in[0];
    const float* W_up   = (const float*)d_in[1];
    const float* W_down = (const float*)d_in[2];
    const float* W_mru  = (const float*)d_in[3];
    const float* g_ln1  = (const float*)d_in[4];
    const float* g_ln2  = (const float*)d_in[5];
    const float* W_mlp1 = (const float*)d_in[6];
    const float* W_mlp2 = (const float*)d_in[7];

    float* out_x     = (float*)d_out;
    float* out_state = (float*)d_out + (size_t)Bb * Ss * Ee;

    float* wsf  = (float*)d_ws;
    float* h    = wsf;                                   // [B,S,E]   4M floats
    float* down = wsf + (size_t)4 * 1024 * 1024;         // [B,S,E]   4M
    float* t1   = wsf + (size_t)8 * 1024 * 1024;         // [B*S,4E] 16M (GEMM2 temp)
    // scan scratch overlaps t1's region (dead before GEMM2 writes t1)
    float* Ttot = wsf + (size_t)8  * 1024 * 1024;        // 2M  [32][64][1024]
    float* Eexc = wsf + (size_t)10 * 1024 * 1024 + 512 * 1024;  // 2M
    float* Utot = wsf + (size_t)13 * 1024 * 1024;        // 256K [32][8][1024]
    float* Wkp  = wsf + (size_t)13 * 1024 * 1024 + 512 * 1024;  // 256K
    float* y    = h;

    const int MT = Bb * Ss;

    ln_kernel<<<MT, 256, 0, stream>>>(act, g_ln1, h);
    scan_pass1<<<512, 256, 0, stream>>>(h, W_up, Ttot);
    scan_pass2a<<<256, 64, 0, stream>>>(Ttot, Eexc, Utot);
    scan_pass2b<<<32, 64, 0, stream>>>(Utot, Wkp);
    scan_pass3<<<512, 256, 0, stream>>>(h, W_up, W_down, Eexc, Wkp, down, out_state);
    {
        dim3 grid(Ee / 64, MT / 64);
        gemm_kernel<false, true><<<grid, 256, 0, stream>>>(down, W_mru, act, out_x, MT, Ee, Ee);
    }
    ln_kernel<<<MT, 256, 0, stream>>>(out_x, g_ln2, y);
    {
        dim3 grid(4 * Ee / 64, MT / 64);
        gemm_kernel<true, false><<<grid, 256, 0, stream>>>(y, W_mlp1, nullptr, t1, MT, 4 * Ee, Ee);
    }
    {
        dim3 grid(Ee / 64, MT / 64);
        gemm_kernel<false, true><<<grid, 256, 0, stream>>>(t1, W_mlp2, out_x, out_x, MT, Ee, 4 * Ee);
    }
}

// Round 3
// 467.693 us; speedup vs baseline: 7.6576x; 3.7364x over previous
//
#include <hip/hip_runtime.h>
#include <hip/hip_bf16.h>
#include <math.h>

#define Bb 2
#define Ss 2048
#define Ee 1024
#define Hh 16
#define Oo 32
#define Cc 2
#define EPSf 1e-5f
#define NSEG 64
#define SEGL 32
#define NGRP 8
#define GRPL 8

typedef __hip_bfloat16 bf16;
typedef __attribute__((ext_vector_type(8))) short short8;
typedef __attribute__((ext_vector_type(4))) float f32x4;

// ---------------- LayerNorm (templated output type) ----------------
template <typename OT>
__global__ __launch_bounds__(256) void ln_kernel(const float* __restrict__ x,
                                                 const float* __restrict__ g,
                                                 OT* __restrict__ out) {
    __shared__ float red[8];
    int row = blockIdx.x;
    const float4* xr = (const float4*)(x + (size_t)row * Ee);
    float4 v = xr[threadIdx.x];
    float s = v.x + v.y + v.z + v.w;
#pragma unroll
    for (int off = 32; off > 0; off >>= 1) s += __shfl_xor(s, off);
    int wave = threadIdx.x >> 6, lane = threadIdx.x & 63;
    if (!lane) red[wave] = s;
    __syncthreads();
    float mu = (red[0] + red[1] + red[2] + red[3]) * (1.0f / Ee);
    float dx = v.x - mu, dy = v.y - mu, dz = v.z - mu, dw = v.w - mu;
    float sq = dx * dx + dy * dy + dz * dz + dw * dw;
#pragma unroll
    for (int off = 32; off > 0; off >>= 1) sq += __shfl_xor(sq, off);
    if (!lane) red[wave + 4] = sq;
    __syncthreads();
    float var = (red[4] + red[5] + red[6] + red[7]) * (1.0f / Ee);
    float rs = rsqrtf(var + EPSf);
    float4 gv = ((const float4*)g)[threadIdx.x];
    float o0 = dx * rs * gv.x, o1 = dy * rs * gv.y, o2 = dz * rs * gv.z, o3 = dw * rs * gv.w;
    if constexpr (sizeof(OT) == 4) {
        ((float4*)((float*)out + (size_t)row * Ee))[threadIdx.x] = make_float4(o0, o1, o2, o3);
    } else {
        __align__(8) bf16 t[4] = {__float2bfloat16(o0), __float2bfloat16(o1),
                                  __float2bfloat16(o2), __float2bfloat16(o3)};
        ((ushort4*)((unsigned short*)out + (size_t)row * Ee))[threadIdx.x] = *(const ushort4*)t;
    }
}

// ---------------- fp32 -> bf16 convert ----------------
__global__ __launch_bounds__(256) void f2bf_kernel(const float* __restrict__ in,
                                                   bf16* __restrict__ out, int n4) {
    int i = blockIdx.x * 256 + threadIdx.x;
    if (i < n4) {
        float4 v = ((const float4*)in)[i];
        __align__(8) bf16 t[4] = {__float2bfloat16(v.x), __float2bfloat16(v.y),
                                  __float2bfloat16(v.z), __float2bfloat16(v.w)};
        ((ushort4*)out)[i] = *(const ushort4*)t;
    }
}

// ======================= Segmented scan (unchanged math) =======================
__device__ __forceinline__ void rank2_step(const float* __restrict__ ap,
                                           const float* __restrict__ wq,
                                           float p[32], float& y0o, float& y1o) {
    float a[64];
#pragma unroll
    for (int j = 0; j < 16; ++j) ((float4*)a)[j] = ((const float4*)ap)[j];
    float s0 = 0.f, s1 = 0.f, s2 = 0.f, s3 = 0.f;
    float u0 = 0.f, u1 = 0.f, u2 = 0.f, u3 = 0.f;
#pragma unroll
    for (int q = 0; q < 32; q += 4) {
        s0 = fmaf(p[q + 0], a[2 * q + 0], s0);
        s1 = fmaf(p[q + 1], a[2 * q + 2], s1);
        s2 = fmaf(p[q + 2], a[2 * q + 4], s2);
        s3 = fmaf(p[q + 3], a[2 * q + 6], s3);
        u0 = fmaf(p[q + 0], a[2 * q + 1], u0);
        u1 = fmaf(p[q + 1], a[2 * q + 3], u1);
        u2 = fmaf(p[q + 2], a[2 * q + 5], u2);
        u3 = fmaf(p[q + 3], a[2 * q + 7], u3);
    }
    float y0 = (s0 + s1) + (s2 + s3);
    float y1 = (u0 + u1) + (u2 + u3);
#pragma unroll
    for (int q = 0; q < 32; ++q) p[q] = fmaf(y0, wq[2 * q], fmaf(y1, wq[2 * q + 1], p[q]));
    y0o = y0; y1o = y1;
}

__device__ __forceinline__ void row_matmul(float e[32], const float* __restrict__ T) {
    float r[32];
#pragma unroll
    for (int q = 0; q < 32; ++q) r[q] = 0.f;
#pragma unroll
    for (int kk = 0; kk < 32; ++kk) {
        float ekk = e[kk];
        const float4* tr = (const float4*)(T + kk * 32);
#pragma unroll
        for (int j = 0; j < 8; ++j) {
            float4 tv = tr[j];
            r[4 * j + 0] = fmaf(ekk, tv.x, r[4 * j + 0]);
            r[4 * j + 1] = fmaf(ekk, tv.y, r[4 * j + 1]);
            r[4 * j + 2] = fmaf(ekk, tv.z, r[4 * j + 2]);
            r[4 * j + 3] = fmaf(ekk, tv.w, r[4 * j + 3]);
        }
    }
#pragma unroll
    for (int q = 0; q < 32; ++q) e[q] = r[q];
}

__global__ __launch_bounds__(256) void scan_pass1(const float* __restrict__ h,
                                                  const float* __restrict__ Wup,
                                                  float* __restrict__ Ttot) {
    int wv = __builtin_amdgcn_readfirstlane((int)(threadIdx.x >> 6));
    int lane = threadIdx.x & 63;
    int o = lane & 31;
    int seg = blockIdx.x * 4 + wv;
    int chain = seg >> 6;
    int g = seg & 63;
    int b = chain >> 4, head = chain & 15;

    float wq[64];
#pragma unroll
    for (int j = 0; j < 16; ++j) ((float4*)wq)[j] = ((const float4*)Wup)[j];
    float p[32];
#pragma unroll
    for (int q = 0; q < 32; ++q) p[q] = (q == o) ? 1.0f : 0.0f;

    const float* hb = h + ((size_t)b * Ss + (size_t)g * SEGL) * Ee + head * 64;
    for (int st = 0; st < SEGL; ++st) {
        float y0, y1;
        rank2_step(hb + (size_t)st * Ee, wq, p, y0, y1);
    }
    if (lane < 32) {
        float* tb = Ttot + ((size_t)chain * NSEG + g) * 1024 + o * 32;
#pragma unroll
        for (int j = 0; j < 8; ++j)
            ((float4*)tb)[j] = make_float4(p[4 * j], p[4 * j + 1], p[4 * j + 2], p[4 * j + 3]);
    }
}

__global__ __launch_bounds__(64) void scan_pass2a(const float* __restrict__ Ttot,
                                                  float* __restrict__ Eexc,
                                                  float* __restrict__ Utot) {
    int lane = threadIdx.x & 63;
    int o = lane & 31;
    int grp = blockIdx.x;
    int chain = grp >> 3, k = grp & 7;
    float e[32];
#pragma unroll
    for (int q = 0; q < 32; ++q) e[q] = (q == o) ? 1.0f : 0.0f;
    for (int i = 0; i < GRPL; ++i) {
        int g = k * GRPL + i;
        if (lane < 32) {
            float* eb = Eexc + ((size_t)chain * NSEG + g) * 1024 + o * 32;
#pragma unroll
            for (int j = 0; j < 8; ++j)
                ((float4*)eb)[j] = make_float4(e[4 * j], e[4 * j + 1], e[4 * j + 2], e[4 * j + 3]);
        }
        row_matmul(e, Ttot + ((size_t)chain * NSEG + g) * 1024);
    }
    if (lane < 32) {
        float* ub = Utot + ((size_t)chain * NGRP + k) * 1024 + o * 32;
#pragma unroll
        for (int j = 0; j < 8; ++j)
            ((float4*)ub)[j] = make_float4(e[4 * j], e[4 * j + 1], e[4 * j + 2], e[4 * j + 3]);
    }
}

__global__ __launch_bounds__(64) void scan_pass2b(const float* __restrict__ Utot,
                                                  float* __restrict__ Wkp) {
    int lane = threadIdx.x & 63;
    int o = lane & 31;
    int chain = blockIdx.x;
    float w[32];
#pragma unroll
    for (int q = 0; q < 32; ++q) w[q] = (q == o) ? 1.0f : 0.0f;
    for (int k = 0; k < NGRP; ++k) {
        if (lane < 32) {
            float* wb = Wkp + ((size_t)chain * NGRP + k) * 1024 + o * 32;
#pragma unroll
            for (int j = 0; j < 8; ++j)
                ((float4*)wb)[j] = make_float4(w[4 * j], w[4 * j + 1], w[4 * j + 2], w[4 * j + 3]);
        }
        row_matmul(w, Utot + ((size_t)chain * NGRP + k) * 1024);
    }
}

__global__ __launch_bounds__(256) void scan_pass3(const float* __restrict__ h,
                                                  const float* __restrict__ Wup,
                                                  const float* __restrict__ Wdn,
                                                  const float* __restrict__ Eexc,
                                                  const float* __restrict__ Wkp,
                                                  bf16* __restrict__ down,
                                                  float* __restrict__ state_out) {
    int wv = __builtin_amdgcn_readfirstlane((int)(threadIdx.x >> 6));
    int lane = threadIdx.x & 63;
    int o = lane & 31;
    int seg = blockIdx.x * 4 + wv;
    int chain = seg >> 6;
    int g = seg & 63;
    int b = chain >> 4, head = chain & 15;
    int k = g >> 3;

    float wq[64];
#pragma unroll
    for (int j = 0; j < 16; ++j) ((float4*)wq)[j] = ((const float4*)Wup)[j];
    float wd[64];
#pragma unroll
    for (int j = 0; j < 16; ++j) ((float4*)wd)[j] = ((const float4*)Wdn)[j];

    float G00 = 0.f, G01 = 0.f, G10 = 0.f, G11 = 0.f;
#pragma unroll
    for (int q = 0; q < 32; ++q) {
        G00 = fmaf(wq[2 * q + 0], wd[q], G00);
        G01 = fmaf(wq[2 * q + 0], wd[32 + q], G01);
        G10 = fmaf(wq[2 * q + 1], wd[q], G10);
        G11 = fmaf(wq[2 * q + 1], wd[32 + q], G11);
    }

    float wrow[32];
    const float* wb = Wkp + ((size_t)chain * NGRP + k) * 1024 + o * 32;
#pragma unroll
    for (int j = 0; j < 8; ++j) ((float4*)wrow)[j] = ((const float4*)wb)[j];
    const float* Eb = Eexc + ((size_t)chain * NSEG + g) * 1024;
    float p[32];
#pragma unroll
    for (int q = 0; q < 32; ++q) p[q] = 0.f;
#pragma unroll
    for (int kk = 0; kk < 32; ++kk) {
        float wkk = wrow[kk];
        const float4* er = (const float4*)(Eb + kk * 32);
#pragma unroll
        for (int j = 0; j < 8; ++j) {
            float4 ev = er[j];
            p[4 * j + 0] = fmaf(wkk, ev.x, p[4 * j + 0]);
            p[4 * j + 1] = fmaf(wkk, ev.y, p[4 * j + 1]);
            p[4 * j + 2] = fmaf(wkk, ev.z, p[4 * j + 2]);
            p[4 * j + 3] = fmaf(wkk, ev.w, p[4 * j + 3]);
        }
    }

    float d0 = 0.f, d1 = 0.f;
#pragma unroll
    for (int q = 0; q < 32; ++q) {
        d0 = fmaf(p[q], wd[q], d0);
        d1 = fmaf(p[q], wd[32 + q], d1);
    }

    const float* hb = h + ((size_t)b * Ss + (size_t)g * SEGL) * Ee + head * 64;
    bf16* db = down + ((size_t)b * Ss + (size_t)g * SEGL) * Ee + head * 64 + o * 2;
    float* sb = state_out + ((size_t)g * SEGL * Hh + head) * 1024 + o * 32;

    for (int st = 0; st < SEGL; ++st) {
        float y0, y1;
        rank2_step(hb + (size_t)st * Ee, wq, p, y0, y1);
        d0 = fmaf(y0, G00, fmaf(y1, G10, d0));
        d1 = fmaf(y0, G01, fmaf(y1, G11, d1));
        if (lane < 32) {
            __hip_bfloat162 dv;
            dv.x = __float2bfloat16(d0);
            dv.y = __float2bfloat16(d1);
            *(__hip_bfloat162*)(db + (size_t)st * Ee) = dv;
            if (b == Bb - 1) {
                float* sp = sb + (size_t)st * (Hh * 1024);
#pragma unroll
                for (int j = 0; j < 8; ++j)
                    ((float4*)sp)[j] = make_float4(p[4 * j], p[4 * j + 1], p[4 * j + 2], p[4 * j + 3]);
            }
        }
    }
}

// ================= bf16 MFMA GEMM (m97 structure): C = A[M,K] @ W[N,K]^T =================
__device__ __forceinline__ void load_lds16(const bf16* g, short* l) {
    __builtin_amdgcn_global_load_lds((const __attribute__((address_space(1))) unsigned int*)g,
                                     (__attribute__((address_space(3))) unsigned int*)l,
                                     16, 0, 0);
}

template <bool GELU, bool RESID, bool BF16OUT>
__global__ __launch_bounds__(256) void mgemm(const bf16* __restrict__ A,
                                             const bf16* __restrict__ Wt,
                                             const float* __restrict__ res,
                                             float* __restrict__ Cf,
                                             bf16* __restrict__ Cb,
                                             int M, int N, int K) {
    __shared__ __align__(16) short As[128 * 32];
    __shared__ __align__(16) short Bs[128 * 32];
    int tid = threadIdx.x;
    int w = __builtin_amdgcn_readfirstlane(tid >> 6);
    int l = tid & 63;
    int bm = blockIdx.y, bn = blockIdx.x;
    int wr = w >> 1, wc = w & 1;

    // staging: 2 chunks per operand; chunk c, wave w, lane l covers bf16 flat idx
    // f = c*2048 + w*512 + l*8 of the [128][32] tile (row = f>>5, col = f&31)
    int f0 = w * 512 + l * 8;
    int r0 = f0 >> 5, c0 = f0 & 31;
    int f1 = 2048 + f0;
    int r1 = f1 >> 5, c1 = f1 & 31;
    const bf16* ga0 = A + (size_t)(bm * 128 + r0) * K + c0;
    const bf16* ga1 = A + (size_t)(bm * 128 + r1) * K + c1;
    const bf16* gb0 = Wt + (size_t)(bn * 128 + r0) * K + c0;
    const bf16* gb1 = Wt + (size_t)(bn * 128 + r1) * K + c1;
    short* la0 = As + w * 512;          // wave-uniform LDS base; HW adds lane*16B
    short* la1 = As + 2048 + w * 512;
    short* lb0 = Bs + w * 512;
    short* lb1 = Bs + 2048 + w * 512;

    f32x4 acc[4][4];
#pragma unroll
    for (int m = 0; m < 4; ++m)
#pragma unroll
        for (int n = 0; n < 4; ++n) acc[m][n] = (f32x4){0.f, 0.f, 0.f, 0.f};

    int lr = l & 15, lk = (l >> 4) * 8;

    for (int k0 = 0; k0 < K; k0 += 32) {
        __syncthreads();
        load_lds16(ga0, la0);
        load_lds16(ga1, la1);
        load_lds16(gb0, lb0);
        load_lds16(gb1, lb1);
        ga0 += 32; ga1 += 32; gb0 += 32; gb1 += 32;
        __syncthreads();
        short8 af[4], bfr[4];
#pragma unroll
        for (int m = 0; m < 4; ++m)
            af[m] = *(const short8*)&As[(wr * 64 + m * 16 + lr) * 32 + lk];
#pragma unroll
        for (int n = 0; n < 4; ++n)
            bfr[n] = *(const short8*)&Bs[(wc * 64 + n * 16 + lr) * 32 + lk];
#pragma unroll
        for (int m = 0; m < 4; ++m)
#pragma unroll
            for (int n = 0; n < 4; ++n)
                acc[m][n] = __builtin_amdgcn_mfma_f32_16x16x32_bf16(af[m], bfr[n], acc[m][n], 0, 0, 0);
    }

#pragma unroll
    for (int m = 0; m < 4; ++m) {
#pragma unroll
        for (int n = 0; n < 4; ++n) {
            int gr0 = bm * 128 + wr * 64 + m * 16 + (l >> 4) * 4;
            int gc = bn * 128 + wc * 64 + n * 16 + (l & 15);
#pragma unroll
            for (int j = 0; j < 4; ++j) {
                float v = acc[m][n][j];
                if (GELU) v = 0.5f * v * (1.0f + erff(v * 0.70710678118654752f));
                if (RESID) v += res[(size_t)(gr0 + j) * N + gc];
                if (BF16OUT) Cb[(size_t)(gr0 + j) * N + gc] = __float2bfloat16(v);
                else Cf[(size_t)(gr0 + j) * N + gc] = v;
            }
        }
    }
}

extern "C" void kernel_launch(void* const* d_in, const int* in_sizes, int n_in,
                              void* d_out, int out_size, void* d_ws, size_t ws_size,
                              hipStream_t stream) {
    const float* act    = (const float*)d_in[0];
    const float* W_up   = (const float*)d_in[1];
    const float* W_down = (const float*)d_in[2];
    const float* W_mru  = (const float*)d_in[3];
    const float* g_ln1  = (const float*)d_in[4];
    const float* g_ln2  = (const float*)d_in[5];
    const float* W_mlp1 = (const float*)d_in[6];
    const float* W_mlp2 = (const float*)d_in[7];

    float* out_x     = (float*)d_out;
    float* out_state = (float*)d_out + (size_t)Bb * Ss * Ee;

    float* wsf = (float*)d_ws;
    const size_t Mfl = 1024 * 1024;
    float* h        = wsf;                          // [0,4M) fp32 LN1 out
    bf16*  down_bf  = (bf16*)(wsf + 4 * Mfl);       // [4M,6M) 4M bf16
    bf16*  y_bf     = (bf16*)(wsf + 6 * Mfl);       // [6M,8M) 4M bf16
    bf16*  t1_bf    = (bf16*)(wsf + 8 * Mfl);       // [8M,16M) 16M bf16
    // scan scratch overlaps t1 region (dead before t1 written)
    float* Ttot = wsf + 8 * Mfl;                    // 2M floats
    float* Eexc = wsf + 10 * Mfl;                   // 2M floats
    float* Utot = wsf + 12 * Mfl;                   // 256K floats
    float* Wkp  = wsf + 12 * Mfl + 512 * 1024;      // 256K floats
    bf16*  Wmru_bf  = (bf16*)(wsf + 16 * Mfl);      // 1M bf16
    bf16*  Wmlp1_bf = (bf16*)(wsf + 17 * Mfl);      // 4M bf16
    bf16*  Wmlp2_bf = (bf16*)(wsf + 19 * Mfl);      // 4M bf16

    const int MT = Bb * Ss;   // 4096

    f2bf_kernel<<<1024, 256, 0, stream>>>(W_mru, Wmru_bf, (1024 * 1024) / 4);
    f2bf_kernel<<<4096, 256, 0, stream>>>(W_mlp1, Wmlp1_bf, (4 * 1024 * 1024) / 4);
    f2bf_kernel<<<4096, 256, 0, stream>>>(W_mlp2, Wmlp2_bf, (4 * 1024 * 1024) / 4);

    ln_kernel<float><<<MT, 256, 0, stream>>>(act, g_ln1, h);
    scan_pass1<<<512, 256, 0, stream>>>(h, W_up, Ttot);
    scan_pass2a<<<256, 64, 0, stream>>>(Ttot, Eexc, Utot);
    scan_pass2b<<<32, 64, 0, stream>>>(Utot, Wkp);
    scan_pass3<<<512, 256, 0, stream>>>(h, W_up, W_down, Eexc, Wkp, down_bf, out_state);

    {   // x1 = act + down @ W_mru^T
        dim3 grid(Ee / 128, MT / 128);
        mgemm<false, true, false><<<grid, 256, 0, stream>>>(down_bf, Wmru_bf, act, out_x, nullptr,
                                                            MT, Ee, Ee);
    }
    ln_kernel<bf16><<<MT, 256, 0, stream>>>(out_x, g_ln2, y_bf);
    {   // t1 = gelu(y @ W_mlp1^T)  (bf16 out)
        dim3 grid(4 * Ee / 128, MT / 128);
        mgemm<true, false, true><<<grid, 256, 0, stream>>>(y_bf, Wmlp1_bf, nullptr, nullptr, t1_bf,
                                                           MT, 4 * Ee, Ee);
    }
    {   // out_x = x1 + t1 @ W_mlp2^T
        dim3 grid(Ee / 128, MT / 128);
        mgemm<false, true, false><<<grid, 256, 0, stream>>>(t1_bf, Wmlp2_bf, out_x, out_x, nullptr,
                                                            MT, Ee, 4 * Ee);
    }
}

// Round 4
// 461.031 us; speedup vs baseline: 7.7683x; 1.0145x over previous
//
#include <hip/hip_runtime.h>
#include <hip/hip_bf16.h>
#include <math.h>

#define Bb 2
#define Ss 2048
#define Ee 1024
#define Hh 16
#define Oo 32
#define Cc 2
#define EPSf 1e-5f
#define NSEG 64
#define SEGL 32
#define NGRP 8
#define GRPL 8

typedef __hip_bfloat16 bf16;
typedef __attribute__((ext_vector_type(8))) short short8;
typedef __attribute__((ext_vector_type(4))) float f32x4;

// ---------------- LayerNorm (templated output type) ----------------
template <typename OT>
__global__ __launch_bounds__(256) void ln_kernel(const float* __restrict__ x,
                                                 const float* __restrict__ g,
                                                 OT* __restrict__ out) {
    __shared__ float red[8];
    int row = blockIdx.x;
    const float4* xr = (const float4*)(x + (size_t)row * Ee);
    float4 v = xr[threadIdx.x];
    float s = v.x + v.y + v.z + v.w;
#pragma unroll
    for (int off = 32; off > 0; off >>= 1) s += __shfl_xor(s, off);
    int wave = threadIdx.x >> 6, lane = threadIdx.x & 63;
    if (!lane) red[wave] = s;
    __syncthreads();
    float mu = (red[0] + red[1] + red[2] + red[3]) * (1.0f / Ee);
    float dx = v.x - mu, dy = v.y - mu, dz = v.z - mu, dw = v.w - mu;
    float sq = dx * dx + dy * dy + dz * dz + dw * dw;
#pragma unroll
    for (int off = 32; off > 0; off >>= 1) sq += __shfl_xor(sq, off);
    if (!lane) red[wave + 4] = sq;
    __syncthreads();
    float var = (red[4] + red[5] + red[6] + red[7]) * (1.0f / Ee);
    float rs = rsqrtf(var + EPSf);
    float4 gv = ((const float4*)g)[threadIdx.x];
    float o0 = dx * rs * gv.x, o1 = dy * rs * gv.y, o2 = dz * rs * gv.z, o3 = dw * rs * gv.w;
    if constexpr (sizeof(OT) == 4) {
        ((float4*)((float*)out + (size_t)row * Ee))[threadIdx.x] = make_float4(o0, o1, o2, o3);
    } else {
        __align__(8) bf16 t[4] = {__float2bfloat16(o0), __float2bfloat16(o1),
                                  __float2bfloat16(o2), __float2bfloat16(o3)};
        ((ushort4*)((unsigned short*)out + (size_t)row * Ee))[threadIdx.x] = *(const ushort4*)t;
    }
}

// ---------------- fp32 -> bf16 convert ----------------
__global__ __launch_bounds__(256) void f2bf_kernel(const float* __restrict__ in,
                                                   bf16* __restrict__ out, int n4) {
    int i = blockIdx.x * 256 + threadIdx.x;
    if (i < n4) {
        float4 v = ((const float4*)in)[i];
        __align__(8) bf16 t[4] = {__float2bfloat16(v.x), __float2bfloat16(v.y),
                                  __float2bfloat16(v.z), __float2bfloat16(v.w)};
        ((ushort4*)out)[i] = *(const ushort4*)t;
    }
}

// ======================= Segmented scan (unchanged) =======================
__device__ __forceinline__ void rank2_step(const float* __restrict__ ap,
                                           const float* __restrict__ wq,
                                           float p[32], float& y0o, float& y1o) {
    float a[64];
#pragma unroll
    for (int j = 0; j < 16; ++j) ((float4*)a)[j] = ((const float4*)ap)[j];
    float s0 = 0.f, s1 = 0.f, s2 = 0.f, s3 = 0.f;
    float u0 = 0.f, u1 = 0.f, u2 = 0.f, u3 = 0.f;
#pragma unroll
    for (int q = 0; q < 32; q += 4) {
        s0 = fmaf(p[q + 0], a[2 * q + 0], s0);
        s1 = fmaf(p[q + 1], a[2 * q + 2], s1);
        s2 = fmaf(p[q + 2], a[2 * q + 4], s2);
        s3 = fmaf(p[q + 3], a[2 * q + 6], s3);
        u0 = fmaf(p[q + 0], a[2 * q + 1], u0);
        u1 = fmaf(p[q + 1], a[2 * q + 3], u1);
        u2 = fmaf(p[q + 2], a[2 * q + 5], u2);
        u3 = fmaf(p[q + 3], a[2 * q + 7], u3);
    }
    float y0 = (s0 + s1) + (s2 + s3);
    float y1 = (u0 + u1) + (u2 + u3);
#pragma unroll
    for (int q = 0; q < 32; ++q) p[q] = fmaf(y0, wq[2 * q], fmaf(y1, wq[2 * q + 1], p[q]));
    y0o = y0; y1o = y1;
}

__device__ __forceinline__ void row_matmul(float e[32], const float* __restrict__ T) {
    float r[32];
#pragma unroll
    for (int q = 0; q < 32; ++q) r[q] = 0.f;
#pragma unroll
    for (int kk = 0; kk < 32; ++kk) {
        float ekk = e[kk];
        const float4* tr = (const float4*)(T + kk * 32);
#pragma unroll
        for (int j = 0; j < 8; ++j) {
            float4 tv = tr[j];
            r[4 * j + 0] = fmaf(ekk, tv.x, r[4 * j + 0]);
            r[4 * j + 1] = fmaf(ekk, tv.y, r[4 * j + 1]);
            r[4 * j + 2] = fmaf(ekk, tv.z, r[4 * j + 2]);
            r[4 * j + 3] = fmaf(ekk, tv.w, r[4 * j + 3]);
        }
    }
#pragma unroll
    for (int q = 0; q < 32; ++q) e[q] = r[q];
}

__global__ __launch_bounds__(256) void scan_pass1(const float* __restrict__ h,
                                                  const float* __restrict__ Wup,
                                                  float* __restrict__ Ttot) {
    int wv = __builtin_amdgcn_readfirstlane((int)(threadIdx.x >> 6));
    int lane = threadIdx.x & 63;
    int o = lane & 31;
    int seg = blockIdx.x * 4 + wv;
    int chain = seg >> 6;
    int g = seg & 63;
    int b = chain >> 4, head = chain & 15;

    float wq[64];
#pragma unroll
    for (int j = 0; j < 16; ++j) ((float4*)wq)[j] = ((const float4*)Wup)[j];
    float p[32];
#pragma unroll
    for (int q = 0; q < 32; ++q) p[q] = (q == o) ? 1.0f : 0.0f;

    const float* hb = h + ((size_t)b * Ss + (size_t)g * SEGL) * Ee + head * 64;
    for (int st = 0; st < SEGL; ++st) {
        float y0, y1;
        rank2_step(hb + (size_t)st * Ee, wq, p, y0, y1);
    }
    if (lane < 32) {
        float* tb = Ttot + ((size_t)chain * NSEG + g) * 1024 + o * 32;
#pragma unroll
        for (int j = 0; j < 8; ++j)
            ((float4*)tb)[j] = make_float4(p[4 * j], p[4 * j + 1], p[4 * j + 2], p[4 * j + 3]);
    }
}

__global__ __launch_bounds__(64) void scan_pass2a(const float* __restrict__ Ttot,
                                                  float* __restrict__ Eexc,
                                                  float* __restrict__ Utot) {
    int lane = threadIdx.x & 63;
    int o = lane & 31;
    int grp = blockIdx.x;
    int chain = grp >> 3, k = grp & 7;
    float e[32];
#pragma unroll
    for (int q = 0; q < 32; ++q) e[q] = (q == o) ? 1.0f : 0.0f;
    for (int i = 0; i < GRPL; ++i) {
        int g = k * GRPL + i;
        if (lane < 32) {
            float* eb = Eexc + ((size_t)chain * NSEG + g) * 1024 + o * 32;
#pragma unroll
            for (int j = 0; j < 8; ++j)
                ((float4*)eb)[j] = make_float4(e[4 * j], e[4 * j + 1], e[4 * j + 2], e[4 * j + 3]);
        }
        row_matmul(e, Ttot + ((size_t)chain * NSEG + g) * 1024);
    }
    if (lane < 32) {
        float* ub = Utot + ((size_t)chain * NGRP + k) * 1024 + o * 32;
#pragma unroll
        for (int j = 0; j < 8; ++j)
            ((float4*)ub)[j] = make_float4(e[4 * j], e[4 * j + 1], e[4 * j + 2], e[4 * j + 3]);
    }
}

__global__ __launch_bounds__(64) void scan_pass2b(const float* __restrict__ Utot,
                                                  float* __restrict__ Wkp) {
    int lane = threadIdx.x & 63;
    int o = lane & 31;
    int chain = blockIdx.x;
    float w[32];
#pragma unroll
    for (int q = 0; q < 32; ++q) w[q] = (q == o) ? 1.0f : 0.0f;
    for (int k = 0; k < NGRP; ++k) {
        if (lane < 32) {
            float* wb = Wkp + ((size_t)chain * NGRP + k) * 1024 + o * 32;
#pragma unroll
            for (int j = 0; j < 8; ++j)
                ((float4*)wb)[j] = make_float4(w[4 * j], w[4 * j + 1], w[4 * j + 2], w[4 * j + 3]);
        }
        row_matmul(w, Utot + ((size_t)chain * NGRP + k) * 1024);
    }
}

__global__ __launch_bounds__(256) void scan_pass3(const float* __restrict__ h,
                                                  const float* __restrict__ Wup,
                                                  const float* __restrict__ Wdn,
                                                  const float* __restrict__ Eexc,
                                                  const float* __restrict__ Wkp,
                                                  bf16* __restrict__ down,
                                                  float* __restrict__ state_out) {
    int wv = __builtin_amdgcn_readfirstlane((int)(threadIdx.x >> 6));
    int lane = threadIdx.x & 63;
    int o = lane & 31;
    int seg = blockIdx.x * 4 + wv;
    int chain = seg >> 6;
    int g = seg & 63;
    int b = chain >> 4, head = chain & 15;
    int k = g >> 3;

    float wq[64];
#pragma unroll
    for (int j = 0; j < 16; ++j) ((float4*)wq)[j] = ((const float4*)Wup)[j];
    float wd[64];
#pragma unroll
    for (int j = 0; j < 16; ++j) ((float4*)wd)[j] = ((const float4*)Wdn)[j];

    float G00 = 0.f, G01 = 0.f, G10 = 0.f, G11 = 0.f;
#pragma unroll
    for (int q = 0; q < 32; ++q) {
        G00 = fmaf(wq[2 * q + 0], wd[q], G00);
        G01 = fmaf(wq[2 * q + 0], wd[32 + q], G01);
        G10 = fmaf(wq[2 * q + 1], wd[q], G10);
        G11 = fmaf(wq[2 * q + 1], wd[32 + q], G11);
    }

    float wrow[32];
    const float* wb = Wkp + ((size_t)chain * NGRP + k) * 1024 + o * 32;
#pragma unroll
    for (int j = 0; j < 8; ++j) ((float4*)wrow)[j] = ((const float4*)wb)[j];
    const float* Eb = Eexc + ((size_t)chain * NSEG + g) * 1024;
    float p[32];
#pragma unroll
    for (int q = 0; q < 32; ++q) p[q] = 0.f;
#pragma unroll
    for (int kk = 0; kk < 32; ++kk) {
        float wkk = wrow[kk];
        const float4* er = (const float4*)(Eb + kk * 32);
#pragma unroll
        for (int j = 0; j < 8; ++j) {
            float4 ev = er[j];
            p[4 * j + 0] = fmaf(wkk, ev.x, p[4 * j + 0]);
            p[4 * j + 1] = fmaf(wkk, ev.y, p[4 * j + 1]);
            p[4 * j + 2] = fmaf(wkk, ev.z, p[4 * j + 2]);
            p[4 * j + 3] = fmaf(wkk, ev.w, p[4 * j + 3]);
        }
    }

    float d0 = 0.f, d1 = 0.f;
#pragma unroll
    for (int q = 0; q < 32; ++q) {
        d0 = fmaf(p[q], wd[q], d0);
        d1 = fmaf(p[q], wd[32 + q], d1);
    }

    const float* hb = h + ((size_t)b * Ss + (size_t)g * SEGL) * Ee + head * 64;
    bf16* db = down + ((size_t)b * Ss + (size_t)g * SEGL) * Ee + head * 64 + o * 2;
    float* sb = state_out + ((size_t)g * SEGL * Hh + head) * 1024 + o * 32;

    for (int st = 0; st < SEGL; ++st) {
        float y0, y1;
        rank2_step(hb + (size_t)st * Ee, wq, p, y0, y1);
        d0 = fmaf(y0, G00, fmaf(y1, G10, d0));
        d1 = fmaf(y0, G01, fmaf(y1, G11, d1));
        if (lane < 32) {
            __hip_bfloat162 dv;
            dv.x = __float2bfloat16(d0);
            dv.y = __float2bfloat16(d1);
            *(__hip_bfloat162*)(db + (size_t)st * Ee) = dv;
            if (b == Bb - 1) {
                float* sp = sb + (size_t)st * (Hh * 1024);
#pragma unroll
                for (int j = 0; j < 8; ++j)
                    ((float4*)sp)[j] = make_float4(p[4 * j], p[4 * j + 1], p[4 * j + 2], p[4 * j + 3]);
            }
        }
    }
}

// ================= bf16 MFMA GEMM: C = A[M,K] @ W[N,K]^T =================
// 128x128 tile, BK=64, XCD-chunked + 8x8-supertile block order.
__device__ __forceinline__ void load_lds16(const bf16* g, short* l) {
    __builtin_amdgcn_global_load_lds((const __attribute__((address_space(1))) unsigned int*)g,
                                     (__attribute__((address_space(3))) unsigned int*)l,
                                     16, 0, 0);
}

template <bool GELU, bool RESID, bool BF16OUT>
__global__ __launch_bounds__(256) void mgemm(const bf16* __restrict__ A,
                                             const bf16* __restrict__ Wt,
                                             const float* __restrict__ res,
                                             float* __restrict__ Cf,
                                             bf16* __restrict__ Cb,
                                             int M, int N, int K) {
    __shared__ __align__(16) short As[128 * 64];
    __shared__ __align__(16) short Bs[128 * 64];
    int tid = threadIdx.x;
    int w = __builtin_amdgcn_readfirstlane(tid >> 6);
    int l = tid & 63;

    // block remap: XCD chunk (bid%8 -> contiguous v-range) + 8x8 supertiles.
    // requires nbm%8==0 && nbn%8==0 (true for all 3 GEMMs here).
    int nbm = M >> 7, nbn = N >> 7;
    int nwg = nbm * nbn;
    int cpx = nwg >> 3;
    int v = ((int)blockIdx.x & 7) * cpx + ((int)blockIdx.x >> 3);
    int sq = v >> 6, rem = v & 63;
    int sqPerRow = nbn >> 3;
    int bm = (sq / sqPerRow) * 8 + (rem >> 3);
    int bn = (sq % sqPerRow) * 8 + (rem & 7);

    int wr = w >> 1, wc = w & 1;

    // staging: round rnd covers rows rnd*32 + w*8 + (l>>3), cols (l&7)*8 of the [128][64] tile
    int srow = w * 8 + (l >> 3);
    int scol = (l & 7) * 8;
    const bf16* ga = A + (size_t)(bm * 128 + srow) * K + scol;
    const bf16* gb = Wt + (size_t)(bn * 128 + srow) * K + scol;
    short* la = As + w * 512;            // wave-uniform LDS base; HW adds lane*16B
    short* lb = Bs + w * 512;

    f32x4 acc[4][4];
#pragma unroll
    for (int m = 0; m < 4; ++m)
#pragma unroll
        for (int n = 0; n < 4; ++n) acc[m][n] = (f32x4){0.f, 0.f, 0.f, 0.f};

    int lr = l & 15, lk = (l >> 4) * 8;

    for (int k0 = 0; k0 < K; k0 += 64) {
        __syncthreads();
#pragma unroll
        for (int rnd = 0; rnd < 4; ++rnd) {
            load_lds16(ga + (size_t)(rnd * 32) * K, la + rnd * 2048);
            load_lds16(gb + (size_t)(rnd * 32) * K, lb + rnd * 2048);
        }
        ga += 64; gb += 64;
        __syncthreads();
        short8 af[2][4], bfr[2][4];
#pragma unroll
        for (int kk = 0; kk < 2; ++kk) {
#pragma unroll
            for (int m = 0; m < 4; ++m)
                af[kk][m] = *(const short8*)&As[(wr * 64 + m * 16 + lr) * 64 + kk * 32 + lk];
#pragma unroll
            for (int n = 0; n < 4; ++n)
                bfr[kk][n] = *(const short8*)&Bs[(wc * 64 + n * 16 + lr) * 64 + kk * 32 + lk];
        }
#pragma unroll
        for (int kk = 0; kk < 2; ++kk)
#pragma unroll
            for (int m = 0; m < 4; ++m)
#pragma unroll
                for (int n = 0; n < 4; ++n)
                    acc[m][n] = __builtin_amdgcn_mfma_f32_16x16x32_bf16(af[kk][m], bfr[kk][n],
                                                                        acc[m][n], 0, 0, 0);
    }

#pragma unroll
    for (int m = 0; m < 4; ++m) {
#pragma unroll
        for (int n = 0; n < 4; ++n) {
            int gr0 = bm * 128 + wr * 64 + m * 16 + (l >> 4) * 4;
            int gc = bn * 128 + wc * 64 + n * 16 + (l & 15);
#pragma unroll
            for (int j = 0; j < 4; ++j) {
                float v2 = acc[m][n][j];
                if (GELU) v2 = 0.5f * v2 * (1.0f + erff(v2 * 0.70710678118654752f));
                if (RESID) v2 += res[(size_t)(gr0 + j) * N + gc];
                if (BF16OUT) Cb[(size_t)(gr0 + j) * N + gc] = __float2bfloat16(v2);
                else Cf[(size_t)(gr0 + j) * N + gc] = v2;
            }
        }
    }
}

extern "C" void kernel_launch(void* const* d_in, const int* in_sizes, int n_in,
                              void* d_out, int out_size, void* d_ws, size_t ws_size,
                              hipStream_t stream) {
    const float* act    = (const float*)d_in[0];
    const float* W_up   = (const float*)d_in[1];
    const float* W_down = (const float*)d_in[2];
    const float* W_mru  = (const float*)d_in[3];
    const float* g_ln1  = (const float*)d_in[4];
    const float* g_ln2  = (const float*)d_in[5];
    const float* W_mlp1 = (const float*)d_in[6];
    const float* W_mlp2 = (const float*)d_in[7];

    float* out_x     = (float*)d_out;
    float* out_state = (float*)d_out + (size_t)Bb * Ss * Ee;

    float* wsf = (float*)d_ws;
    const size_t Mfl = 1024 * 1024;
    float* h        = wsf;                          // [0,4M) fp32 LN1 out
    bf16*  down_bf  = (bf16*)(wsf + 4 * Mfl);       // [4M,6M) 4M bf16
    bf16*  y_bf     = (bf16*)(wsf + 6 * Mfl);       // [6M,8M) 4M bf16
    bf16*  t1_bf    = (bf16*)(wsf + 8 * Mfl);       // [8M,16M) 16M bf16
    // scan scratch overlaps t1 region (dead before t1 written)
    float* Ttot = wsf + 8 * Mfl;                    // 2M floats
    float* Eexc = wsf + 10 * Mfl;                   // 2M floats
    float* Utot = wsf + 12 * Mfl;                   // 256K floats
    float* Wkp  = wsf + 12 * Mfl + 512 * 1024;      // 256K floats
    bf16*  Wmru_bf  = (bf16*)(wsf + 16 * Mfl);      // 1M bf16
    bf16*  Wmlp1_bf = (bf16*)(wsf + 17 * Mfl);      // 4M bf16
    bf16*  Wmlp2_bf = (bf16*)(wsf + 19 * Mfl);      // 4M bf16

    const int MT = Bb * Ss;   // 4096

    f2bf_kernel<<<1024, 256, 0, stream>>>(W_mru, Wmru_bf, (1024 * 1024) / 4);
    f2bf_kernel<<<4096, 256, 0, stream>>>(W_mlp1, Wmlp1_bf, (4 * 1024 * 1024) / 4);
    f2bf_kernel<<<4096, 256, 0, stream>>>(W_mlp2, Wmlp2_bf, (4 * 1024 * 1024) / 4);

    ln_kernel<float><<<MT, 256, 0, stream>>>(act, g_ln1, h);
    scan_pass1<<<512, 256, 0, stream>>>(h, W_up, Ttot);
    scan_pass2a<<<256, 64, 0, stream>>>(Ttot, Eexc, Utot);
    scan_pass2b<<<32, 64, 0, stream>>>(Utot, Wkp);
    scan_pass3<<<512, 256, 0, stream>>>(h, W_up, W_down, Eexc, Wkp, down_bf, out_state);

    {   // x1 = act + down @ W_mru^T
        mgemm<false, true, false><<<(MT / 128) * (Ee / 128), 256, 0, stream>>>(
            down_bf, Wmru_bf, act, out_x, nullptr, MT, Ee, Ee);
    }
    ln_kernel<bf16><<<MT, 256, 0, stream>>>(out_x, g_ln2, y_bf);
    {   // t1 = gelu(y @ W_mlp1^T)  (bf16 out)
        mgemm<true, false, true><<<(MT / 128) * (4 * Ee / 128), 256, 0, stream>>>(
            y_bf, Wmlp1_bf, nullptr, nullptr, t1_bf, MT, 4 * Ee, Ee);
    }
    {   // out_x = x1 + t1 @ W_mlp2^T
        mgemm<false, true, false><<<(MT / 128) * (Ee / 128), 256, 0, stream>>>(
            t1_bf, Wmlp2_bf, out_x, out_x, nullptr, MT, Ee, 4 * Ee);
    }
}

// Round 5
// 455.548 us; speedup vs baseline: 7.8618x; 1.0120x over previous
//
#include <hip/hip_runtime.h>
#include <hip/hip_bf16.h>
#include <math.h>

#define Bb 2
#define Ss 2048
#define Ee 1024
#define Hh 16
#define Oo 32
#define Cc 2
#define EPSf 1e-5f
#define NSEG 64
#define SEGL 32
#define NGRP 8
#define GRPL 8

typedef __hip_bfloat16 bf16;
typedef __attribute__((ext_vector_type(8))) short short8;
typedef __attribute__((ext_vector_type(4))) float f32x4;

// ---------------- LayerNorm (templated output type) ----------------
template <typename OT>
__global__ __launch_bounds__(256) void ln_kernel(const float* __restrict__ x,
                                                 const float* __restrict__ g,
                                                 OT* __restrict__ out) {
    __shared__ float red[8];
    int row = blockIdx.x;
    const float4* xr = (const float4*)(x + (size_t)row * Ee);
    float4 v = xr[threadIdx.x];
    float s = v.x + v.y + v.z + v.w;
#pragma unroll
    for (int off = 32; off > 0; off >>= 1) s += __shfl_xor(s, off);
    int wave = threadIdx.x >> 6, lane = threadIdx.x & 63;
    if (!lane) red[wave] = s;
    __syncthreads();
    float mu = (red[0] + red[1] + red[2] + red[3]) * (1.0f / Ee);
    float dx = v.x - mu, dy = v.y - mu, dz = v.z - mu, dw = v.w - mu;
    float sq = dx * dx + dy * dy + dz * dz + dw * dw;
#pragma unroll
    for (int off = 32; off > 0; off >>= 1) sq += __shfl_xor(sq, off);
    if (!lane) red[wave + 4] = sq;
    __syncthreads();
    float var = (red[4] + red[5] + red[6] + red[7]) * (1.0f / Ee);
    float rs = rsqrtf(var + EPSf);
    float4 gv = ((const float4*)g)[threadIdx.x];
    float o0 = dx * rs * gv.x, o1 = dy * rs * gv.y, o2 = dz * rs * gv.z, o3 = dw * rs * gv.w;
    if constexpr (sizeof(OT) == 4) {
        ((float4*)((float*)out + (size_t)row * Ee))[threadIdx.x] = make_float4(o0, o1, o2, o3);
    } else {
        __align__(8) bf16 t[4] = {__float2bfloat16(o0), __float2bfloat16(o1),
                                  __float2bfloat16(o2), __float2bfloat16(o3)};
        ((ushort4*)((unsigned short*)out + (size_t)row * Ee))[threadIdx.x] = *(const ushort4*)t;
    }
}

// ---------------- fp32 -> bf16 convert ----------------
__global__ __launch_bounds__(256) void f2bf_kernel(const float* __restrict__ in,
                                                   bf16* __restrict__ out, int n4) {
    int i = blockIdx.x * 256 + threadIdx.x;
    if (i < n4) {
        float4 v = ((const float4*)in)[i];
        __align__(8) bf16 t[4] = {__float2bfloat16(v.x), __float2bfloat16(v.y),
                                  __float2bfloat16(v.z), __float2bfloat16(v.w)};
        ((ushort4*)out)[i] = *(const ushort4*)t;
    }
}

// ======================= Segmented scan (unchanged) =======================
__device__ __forceinline__ void rank2_step(const float* __restrict__ ap,
                                           const float* __restrict__ wq,
                                           float p[32], float& y0o, float& y1o) {
    float a[64];
#pragma unroll
    for (int j = 0; j < 16; ++j) ((float4*)a)[j] = ((const float4*)ap)[j];
    float s0 = 0.f, s1 = 0.f, s2 = 0.f, s3 = 0.f;
    float u0 = 0.f, u1 = 0.f, u2 = 0.f, u3 = 0.f;
#pragma unroll
    for (int q = 0; q < 32; q += 4) {
        s0 = fmaf(p[q + 0], a[2 * q + 0], s0);
        s1 = fmaf(p[q + 1], a[2 * q + 2], s1);
        s2 = fmaf(p[q + 2], a[2 * q + 4], s2);
        s3 = fmaf(p[q + 3], a[2 * q + 6], s3);
        u0 = fmaf(p[q + 0], a[2 * q + 1], u0);
        u1 = fmaf(p[q + 1], a[2 * q + 3], u1);
        u2 = fmaf(p[q + 2], a[2 * q + 5], u2);
        u3 = fmaf(p[q + 3], a[2 * q + 7], u3);
    }
    float y0 = (s0 + s1) + (s2 + s3);
    float y1 = (u0 + u1) + (u2 + u3);
#pragma unroll
    for (int q = 0; q < 32; ++q) p[q] = fmaf(y0, wq[2 * q], fmaf(y1, wq[2 * q + 1], p[q]));
    y0o = y0; y1o = y1;
}

__device__ __forceinline__ void row_matmul(float e[32], const float* __restrict__ T) {
    float r[32];
#pragma unroll
    for (int q = 0; q < 32; ++q) r[q] = 0.f;
#pragma unroll
    for (int kk = 0; kk < 32; ++kk) {
        float ekk = e[kk];
        const float4* tr = (const float4*)(T + kk * 32);
#pragma unroll
        for (int j = 0; j < 8; ++j) {
            float4 tv = tr[j];
            r[4 * j + 0] = fmaf(ekk, tv.x, r[4 * j + 0]);
            r[4 * j + 1] = fmaf(ekk, tv.y, r[4 * j + 1]);
            r[4 * j + 2] = fmaf(ekk, tv.z, r[4 * j + 2]);
            r[4 * j + 3] = fmaf(ekk, tv.w, r[4 * j + 3]);
        }
    }
#pragma unroll
    for (int q = 0; q < 32; ++q) e[q] = r[q];
}

__global__ __launch_bounds__(256) void scan_pass1(const float* __restrict__ h,
                                                  const float* __restrict__ Wup,
                                                  float* __restrict__ Ttot) {
    int wv = __builtin_amdgcn_readfirstlane((int)(threadIdx.x >> 6));
    int lane = threadIdx.x & 63;
    int o = lane & 31;
    int seg = blockIdx.x * 4 + wv;
    int chain = seg >> 6;
    int g = seg & 63;
    int b = chain >> 4, head = chain & 15;

    float wq[64];
#pragma unroll
    for (int j = 0; j < 16; ++j) ((float4*)wq)[j] = ((const float4*)Wup)[j];
    float p[32];
#pragma unroll
    for (int q = 0; q < 32; ++q) p[q] = (q == o) ? 1.0f : 0.0f;

    const float* hb = h + ((size_t)b * Ss + (size_t)g * SEGL) * Ee + head * 64;
    for (int st = 0; st < SEGL; ++st) {
        float y0, y1;
        rank2_step(hb + (size_t)st * Ee, wq, p, y0, y1);
    }
    if (lane < 32) {
        float* tb = Ttot + ((size_t)chain * NSEG + g) * 1024 + o * 32;
#pragma unroll
        for (int j = 0; j < 8; ++j)
            ((float4*)tb)[j] = make_float4(p[4 * j], p[4 * j + 1], p[4 * j + 2], p[4 * j + 3]);
    }
}

__global__ __launch_bounds__(64) void scan_pass2a(const float* __restrict__ Ttot,
                                                  float* __restrict__ Eexc,
                                                  float* __restrict__ Utot) {
    int lane = threadIdx.x & 63;
    int o = lane & 31;
    int grp = blockIdx.x;
    int chain = grp >> 3, k = grp & 7;
    float e[32];
#pragma unroll
    for (int q = 0; q < 32; ++q) e[q] = (q == o) ? 1.0f : 0.0f;
    for (int i = 0; i < GRPL; ++i) {
        int g = k * GRPL + i;
        if (lane < 32) {
            float* eb = Eexc + ((size_t)chain * NSEG + g) * 1024 + o * 32;
#pragma unroll
            for (int j = 0; j < 8; ++j)
                ((float4*)eb)[j] = make_float4(e[4 * j], e[4 * j + 1], e[4 * j + 2], e[4 * j + 3]);
        }
        row_matmul(e, Ttot + ((size_t)chain * NSEG + g) * 1024);
    }
    if (lane < 32) {
        float* ub = Utot + ((size_t)chain * NGRP + k) * 1024 + o * 32;
#pragma unroll
        for (int j = 0; j < 8; ++j)
            ((float4*)ub)[j] = make_float4(e[4 * j], e[4 * j + 1], e[4 * j + 2], e[4 * j + 3]);
    }
}

__global__ __launch_bounds__(64) void scan_pass2b(const float* __restrict__ Utot,
                                                  float* __restrict__ Wkp) {
    int lane = threadIdx.x & 63;
    int o = lane & 31;
    int chain = blockIdx.x;
    float w[32];
#pragma unroll
    for (int q = 0; q < 32; ++q) w[q] = (q == o) ? 1.0f : 0.0f;
    for (int k = 0; k < NGRP; ++k) {
        if (lane < 32) {
            float* wb = Wkp + ((size_t)chain * NGRP + k) * 1024 + o * 32;
#pragma unroll
            for (int j = 0; j < 8; ++j)
                ((float4*)wb)[j] = make_float4(w[4 * j], w[4 * j + 1], w[4 * j + 2], w[4 * j + 3]);
        }
        row_matmul(w, Utot + ((size_t)chain * NGRP + k) * 1024);
    }
}

__global__ __launch_bounds__(256) void scan_pass3(const float* __restrict__ h,
                                                  const float* __restrict__ Wup,
                                                  const float* __restrict__ Wdn,
                                                  const float* __restrict__ Eexc,
                                                  const float* __restrict__ Wkp,
                                                  bf16* __restrict__ down,
                                                  float* __restrict__ state_out) {
    int wv = __builtin_amdgcn_readfirstlane((int)(threadIdx.x >> 6));
    int lane = threadIdx.x & 63;
    int o = lane & 31;
    int seg = blockIdx.x * 4 + wv;
    int chain = seg >> 6;
    int g = seg & 63;
    int b = chain >> 4, head = chain & 15;
    int k = g >> 3;

    float wq[64];
#pragma unroll
    for (int j = 0; j < 16; ++j) ((float4*)wq)[j] = ((const float4*)Wup)[j];
    float wd[64];
#pragma unroll
    for (int j = 0; j < 16; ++j) ((float4*)wd)[j] = ((const float4*)Wdn)[j];

    float G00 = 0.f, G01 = 0.f, G10 = 0.f, G11 = 0.f;
#pragma unroll
    for (int q = 0; q < 32; ++q) {
        G00 = fmaf(wq[2 * q + 0], wd[q], G00);
        G01 = fmaf(wq[2 * q + 0], wd[32 + q], G01);
        G10 = fmaf(wq[2 * q + 1], wd[q], G10);
        G11 = fmaf(wq[2 * q + 1], wd[32 + q], G11);
    }

    float wrow[32];
    const float* wb = Wkp + ((size_t)chain * NGRP + k) * 1024 + o * 32;
#pragma unroll
    for (int j = 0; j < 8; ++j) ((float4*)wrow)[j] = ((const float4*)wb)[j];
    const float* Eb = Eexc + ((size_t)chain * NSEG + g) * 1024;
    float p[32];
#pragma unroll
    for (int q = 0; q < 32; ++q) p[q] = 0.f;
#pragma unroll
    for (int kk = 0; kk < 32; ++kk) {
        float wkk = wrow[kk];
        const float4* er = (const float4*)(Eb + kk * 32);
#pragma unroll
        for (int j = 0; j < 8; ++j) {
            float4 ev = er[j];
            p[4 * j + 0] = fmaf(wkk, ev.x, p[4 * j + 0]);
            p[4 * j + 1] = fmaf(wkk, ev.y, p[4 * j + 1]);
            p[4 * j + 2] = fmaf(wkk, ev.z, p[4 * j + 2]);
            p[4 * j + 3] = fmaf(wkk, ev.w, p[4 * j + 3]);
        }
    }

    float d0 = 0.f, d1 = 0.f;
#pragma unroll
    for (int q = 0; q < 32; ++q) {
        d0 = fmaf(p[q], wd[q], d0);
        d1 = fmaf(p[q], wd[32 + q], d1);
    }

    const float* hb = h + ((size_t)b * Ss + (size_t)g * SEGL) * Ee + head * 64;
    bf16* db = down + ((size_t)b * Ss + (size_t)g * SEGL) * Ee + head * 64 + o * 2;
    float* sb = state_out + ((size_t)g * SEGL * Hh + head) * 1024 + o * 32;

    for (int st = 0; st < SEGL; ++st) {
        float y0, y1;
        rank2_step(hb + (size_t)st * Ee, wq, p, y0, y1);
        d0 = fmaf(y0, G00, fmaf(y1, G10, d0));
        d1 = fmaf(y0, G01, fmaf(y1, G11, d1));
        if (lane < 32) {
            __hip_bfloat162 dv;
            dv.x = __float2bfloat16(d0);
            dv.y = __float2bfloat16(d1);
            *(__hip_bfloat162*)(db + (size_t)st * Ee) = dv;
            if (b == Bb - 1) {
                float* sp = sb + (size_t)st * (Hh * 1024);
#pragma unroll
                for (int j = 0; j < 8; ++j)
                    ((float4*)sp)[j] = make_float4(p[4 * j], p[4 * j + 1], p[4 * j + 2], p[4 * j + 3]);
            }
        }
    }
}

// ================= bf16 MFMA GEMM: C = A[M,K] @ W[N,K]^T =================
// 128x128 tile, BK=32, double-buffered LDS with prefetch-under-compute (T3 2-phase),
// XCD-chunked + 8x8-supertile block order.
__device__ __forceinline__ void load_lds16(const bf16* g, short* l) {
    __builtin_amdgcn_global_load_lds((const __attribute__((address_space(1))) unsigned int*)g,
                                     (__attribute__((address_space(3))) unsigned int*)l,
                                     16, 0, 0);
}

template <bool GELU, bool RESID, bool BF16OUT>
__global__ __launch_bounds__(256) void mgemm(const bf16* __restrict__ A,
                                             const bf16* __restrict__ Wt,
                                             const float* __restrict__ res,
                                             float* __restrict__ Cf,
                                             bf16* __restrict__ Cb,
                                             int M, int N, int K) {
    __shared__ __align__(16) short As[2][128 * 32];
    __shared__ __align__(16) short Bs[2][128 * 32];
    int tid = threadIdx.x;
    int w = __builtin_amdgcn_readfirstlane(tid >> 6);
    int l = tid & 63;

    // block remap: XCD chunk + 8x8 supertiles (all grids here have nbm%8==0, nbn%8==0)
    int nbm = M >> 7, nbn = N >> 7;
    int nwg = nbm * nbn;
    int cpx = nwg >> 3;
    int v = ((int)blockIdx.x & 7) * cpx + ((int)blockIdx.x >> 3);
    int sq = v >> 6, rem = v & 63;
    int sqPerRow = nbn >> 3;
    int bm = (sq / sqPerRow) * 8 + (rem >> 3);
    int bn = (sq % sqPerRow) * 8 + (rem & 7);

    int wr = w >> 1, wc = w & 1;

    // staging map: chunk c in {0,1}, wave w, lane l covers bf16 flat idx
    // f = c*2048 + w*512 + l*8 of the [128][32] tile (row = f>>5, col = f&31)
    int f0 = w * 512 + l * 8;
    int r0 = f0 >> 5, c0 = f0 & 31;
    int f1 = 2048 + f0;
    int r1 = f1 >> 5, c1 = f1 & 31;
    const bf16* ga0 = A + (size_t)(bm * 128 + r0) * K + c0;
    const bf16* ga1 = A + (size_t)(bm * 128 + r1) * K + c1;
    const bf16* gb0 = Wt + (size_t)(bn * 128 + r0) * K + c0;
    const bf16* gb1 = Wt + (size_t)(bn * 128 + r1) * K + c1;

    f32x4 acc[4][4];
#pragma unroll
    for (int m = 0; m < 4; ++m)
#pragma unroll
        for (int n = 0; n < 4; ++n) acc[m][n] = (f32x4){0.f, 0.f, 0.f, 0.f};

    int lr = l & 15, lk = (l >> 4) * 8;
    const int NT = K >> 5;

    // prologue: stage tile 0 into buffer 0
    load_lds16(ga0, &As[0][w * 512]);
    load_lds16(ga1, &As[0][2048 + w * 512]);
    load_lds16(gb0, &Bs[0][w * 512]);
    load_lds16(gb1, &Bs[0][2048 + w * 512]);
    ga0 += 32; ga1 += 32; gb0 += 32; gb1 += 32;
    __syncthreads();                      // implicit vmcnt(0): tile 0 landed

    int cur = 0;
    for (int t = 0; t < NT; ++t) {
        if (t + 1 < NT) {                 // issue NEXT tile's loads first (latency hides under compute)
            int nx = cur ^ 1;
            load_lds16(ga0, &As[nx][w * 512]);
            load_lds16(ga1, &As[nx][2048 + w * 512]);
            load_lds16(gb0, &Bs[nx][w * 512]);
            load_lds16(gb1, &Bs[nx][2048 + w * 512]);
            ga0 += 32; ga1 += 32; gb0 += 32; gb1 += 32;
        }
        short8 af[4], bfr[4];
#pragma unroll
        for (int m = 0; m < 4; ++m)
            af[m] = *(const short8*)&As[cur][(wr * 64 + m * 16 + lr) * 32 + lk];
#pragma unroll
        for (int n = 0; n < 4; ++n)
            bfr[n] = *(const short8*)&Bs[cur][(wc * 64 + n * 16 + lr) * 32 + lk];
#pragma unroll
        for (int m = 0; m < 4; ++m)
#pragma unroll
            for (int n = 0; n < 4; ++n)
                acc[m][n] = __builtin_amdgcn_mfma_f32_16x16x32_bf16(af[m], bfr[n], acc[m][n], 0, 0, 0);
        if (t + 1 < NT) {
            __syncthreads();              // drains vmcnt(0): next tile landed; all waves past reads of As[cur]
            cur ^= 1;
        }
    }

#pragma unroll
    for (int m = 0; m < 4; ++m) {
#pragma unroll
        for (int n = 0; n < 4; ++n) {
            int gr0 = bm * 128 + wr * 64 + m * 16 + (l >> 4) * 4;
            int gc = bn * 128 + wc * 64 + n * 16 + (l & 15);
#pragma unroll
            for (int j = 0; j < 4; ++j) {
                float v2 = acc[m][n][j];
                if (GELU) v2 = 0.5f * v2 * (1.0f + erff(v2 * 0.70710678118654752f));
                if (RESID) v2 += res[(size_t)(gr0 + j) * N + gc];
                if (BF16OUT) Cb[(size_t)(gr0 + j) * N + gc] = __float2bfloat16(v2);
                else Cf[(size_t)(gr0 + j) * N + gc] = v2;
            }
        }
    }
}

extern "C" void kernel_launch(void* const* d_in, const int* in_sizes, int n_in,
                              void* d_out, int out_size, void* d_ws, size_t ws_size,
                              hipStream_t stream) {
    const float* act    = (const float*)d_in[0];
    const float* W_up   = (const float*)d_in[1];
    const float* W_down = (const float*)d_in[2];
    const float* W_mru  = (const float*)d_in[3];
    const float* g_ln1  = (const float*)d_in[4];
    const float* g_ln2  = (const float*)d_in[5];
    const float* W_mlp1 = (const float*)d_in[6];
    const float* W_mlp2 = (const float*)d_in[7];

    float* out_x     = (float*)d_out;
    float* out_state = (float*)d_out + (size_t)Bb * Ss * Ee;

    float* wsf = (float*)d_ws;
    const size_t Mfl = 1024 * 1024;
    float* h        = wsf;                          // [0,4M) fp32 LN1 out
    bf16*  down_bf  = (bf16*)(wsf + 4 * Mfl);       // [4M,6M) 4M bf16
    bf16*  y_bf     = (bf16*)(wsf + 6 * Mfl);       // [6M,8M) 4M bf16
    bf16*  t1_bf    = (bf16*)(wsf + 8 * Mfl);       // [8M,16M) 16M bf16
    // scan scratch overlaps t1 region (dead before t1 written)
    float* Ttot = wsf + 8 * Mfl;                    // 2M floats
    float* Eexc = wsf + 10 * Mfl;                   // 2M floats
    float* Utot = wsf + 12 * Mfl;                   // 256K floats
    float* Wkp  = wsf + 12 * Mfl + 512 * 1024;      // 256K floats
    bf16*  Wmru_bf  = (bf16*)(wsf + 16 * Mfl);      // 1M bf16
    bf16*  Wmlp1_bf = (bf16*)(wsf + 17 * Mfl);      // 4M bf16
    bf16*  Wmlp2_bf = (bf16*)(wsf + 19 * Mfl);      // 4M bf16

    const int MT = Bb * Ss;   // 4096

    f2bf_kernel<<<1024, 256, 0, stream>>>(W_mru, Wmru_bf, (1024 * 1024) / 4);
    f2bf_kernel<<<4096, 256, 0, stream>>>(W_mlp1, Wmlp1_bf, (4 * 1024 * 1024) / 4);
    f2bf_kernel<<<4096, 256, 0, stream>>>(W_mlp2, Wmlp2_bf, (4 * 1024 * 1024) / 4);

    ln_kernel<float><<<MT, 256, 0, stream>>>(act, g_ln1, h);
    scan_pass1<<<512, 256, 0, stream>>>(h, W_up, Ttot);
    scan_pass2a<<<256, 64, 0, stream>>>(Ttot, Eexc, Utot);
    scan_pass2b<<<32, 64, 0, stream>>>(Utot, Wkp);
    scan_pass3<<<512, 256, 0, stream>>>(h, W_up, W_down, Eexc, Wkp, down_bf, out_state);

    {   // x1 = act + down @ W_mru^T
        mgemm<false, true, false><<<(MT / 128) * (Ee / 128), 256, 0, stream>>>(
            down_bf, Wmru_bf, act, out_x, nullptr, MT, Ee, Ee);
    }
    ln_kernel<bf16><<<MT, 256, 0, stream>>>(out_x, g_ln2, y_bf);
    {   // t1 = gelu(y @ W_mlp1^T)  (bf16 out)
        mgemm<true, false, true><<<(MT / 128) * (4 * Ee / 128), 256, 0, stream>>>(
            y_bf, Wmlp1_bf, nullptr, nullptr, t1_bf, MT, 4 * Ee, Ee);
    }
    {   // out_x = x1 + t1 @ W_mlp2^T
        mgemm<false, true, false><<<(MT / 128) * (Ee / 128), 256, 0, stream>>>(
            t1_bf, Wmlp2_bf, out_x, out_x, nullptr, MT, Ee, 4 * Ee);
    }
}

// Round 7
// 428.617 us; speedup vs baseline: 8.3558x; 1.0628x over previous
//
#include <hip/hip_runtime.h>
#include <hip/hip_bf16.h>
#include <math.h>

#define Bb 2
#define Ss 2048
#define Ee 1024
#define Hh 16
#define Oo 32
#define Cc 2
#define EPSf 1e-5f
#define NSEG 64
#define SEGL 32
#define NGRP 8
#define GRPL 8

typedef __hip_bfloat16 bf16;
typedef __attribute__((ext_vector_type(8))) short short8;
typedef __attribute__((ext_vector_type(4))) float f32x4;

// ---------------- LayerNorm (templated output type) ----------------
template <typename OT>
__global__ __launch_bounds__(256) void ln_kernel(const float* __restrict__ x,
                                                 const float* __restrict__ g,
                                                 OT* __restrict__ out) {
    __shared__ float red[8];
    int row = blockIdx.x;
    const float4* xr = (const float4*)(x + (size_t)row * Ee);
    float4 v = xr[threadIdx.x];
    float s = v.x + v.y + v.z + v.w;
#pragma unroll
    for (int off = 32; off > 0; off >>= 1) s += __shfl_xor(s, off);
    int wave = threadIdx.x >> 6, lane = threadIdx.x & 63;
    if (!lane) red[wave] = s;
    __syncthreads();
    float mu = (red[0] + red[1] + red[2] + red[3]) * (1.0f / Ee);
    float dx = v.x - mu, dy = v.y - mu, dz = v.z - mu, dw = v.w - mu;
    float sq = dx * dx + dy * dy + dz * dz + dw * dw;
#pragma unroll
    for (int off = 32; off > 0; off >>= 1) sq += __shfl_xor(sq, off);
    if (!lane) red[wave + 4] = sq;
    __syncthreads();
    float var = (red[4] + red[5] + red[6] + red[7]) * (1.0f / Ee);
    float rs = rsqrtf(var + EPSf);
    float4 gv = ((const float4*)g)[threadIdx.x];
    float o0 = dx * rs * gv.x, o1 = dy * rs * gv.y, o2 = dz * rs * gv.z, o3 = dw * rs * gv.w;
    if constexpr (sizeof(OT) == 4) {
        ((float4*)((float*)out + (size_t)row * Ee))[threadIdx.x] = make_float4(o0, o1, o2, o3);
    } else {
        __align__(8) bf16 t[4] = {__float2bfloat16(o0), __float2bfloat16(o1),
                                  __float2bfloat16(o2), __float2bfloat16(o3)};
        ((ushort4*)((unsigned short*)out + (size_t)row * Ee))[threadIdx.x] = *(const ushort4*)t;
    }
}

// ---------------- fp32 -> bf16 convert ----------------
__global__ __launch_bounds__(256) void f2bf_kernel(const float* __restrict__ in,
                                                   bf16* __restrict__ out, int n4) {
    int i = blockIdx.x * 256 + threadIdx.x;
    if (i < n4) {
        float4 v = ((const float4*)in)[i];
        __align__(8) bf16 t[4] = {__float2bfloat16(v.x), __float2bfloat16(v.y),
                                  __float2bfloat16(v.z), __float2bfloat16(v.w)};
        ((ushort4*)out)[i] = *(const ushort4*)t;
    }
}

// ======================= Segmented scan (unchanged) =======================
__device__ __forceinline__ void rank2_step(const float* __restrict__ ap,
                                           const float* __restrict__ wq,
                                           float p[32], float& y0o, float& y1o) {
    float a[64];
#pragma unroll
    for (int j = 0; j < 16; ++j) ((float4*)a)[j] = ((const float4*)ap)[j];
    float s0 = 0.f, s1 = 0.f, s2 = 0.f, s3 = 0.f;
    float u0 = 0.f, u1 = 0.f, u2 = 0.f, u3 = 0.f;
#pragma unroll
    for (int q = 0; q < 32; q += 4) {
        s0 = fmaf(p[q + 0], a[2 * q + 0], s0);
        s1 = fmaf(p[q + 1], a[2 * q + 2], s1);
        s2 = fmaf(p[q + 2], a[2 * q + 4], s2);
        s3 = fmaf(p[q + 3], a[2 * q + 6], s3);
        u0 = fmaf(p[q + 0], a[2 * q + 1], u0);
        u1 = fmaf(p[q + 1], a[2 * q + 3], u1);
        u2 = fmaf(p[q + 2], a[2 * q + 5], u2);
        u3 = fmaf(p[q + 3], a[2 * q + 7], u3);
    }
    float y0 = (s0 + s1) + (s2 + s3);
    float y1 = (u0 + u1) + (u2 + u3);
#pragma unroll
    for (int q = 0; q < 32; ++q) p[q] = fmaf(y0, wq[2 * q], fmaf(y1, wq[2 * q + 1], p[q]));
    y0o = y0; y1o = y1;
}

__device__ __forceinline__ void row_matmul(float e[32], const float* __restrict__ T) {
    float r[32];
#pragma unroll
    for (int q = 0; q < 32; ++q) r[q] = 0.f;
#pragma unroll
    for (int kk = 0; kk < 32; ++kk) {
        float ekk = e[kk];
        const float4* tr = (const float4*)(T + kk * 32);
#pragma unroll
        for (int j = 0; j < 8; ++j) {
            float4 tv = tr[j];
            r[4 * j + 0] = fmaf(ekk, tv.x, r[4 * j + 0]);
            r[4 * j + 1] = fmaf(ekk, tv.y, r[4 * j + 1]);
            r[4 * j + 2] = fmaf(ekk, tv.z, r[4 * j + 2]);
            r[4 * j + 3] = fmaf(ekk, tv.w, r[4 * j + 3]);
        }
    }
#pragma unroll
    for (int q = 0; q < 32; ++q) e[q] = r[q];
}

__global__ __launch_bounds__(256) void scan_pass1(const float* __restrict__ h,
                                                  const float* __restrict__ Wup,
                                                  float* __restrict__ Ttot) {
    int wv = __builtin_amdgcn_readfirstlane((int)(threadIdx.x >> 6));
    int lane = threadIdx.x & 63;
    int o = lane & 31;
    int seg = blockIdx.x * 4 + wv;
    int chain = seg >> 6;
    int g = seg & 63;
    int b = chain >> 4, head = chain & 15;

    float wq[64];
#pragma unroll
    for (int j = 0; j < 16; ++j) ((float4*)wq)[j] = ((const float4*)Wup)[j];
    float p[32];
#pragma unroll
    for (int q = 0; q < 32; ++q) p[q] = (q == o) ? 1.0f : 0.0f;

    const float* hb = h + ((size_t)b * Ss + (size_t)g * SEGL) * Ee + head * 64;
    for (int st = 0; st < SEGL; ++st) {
        float y0, y1;
        rank2_step(hb + (size_t)st * Ee, wq, p, y0, y1);
    }
    if (lane < 32) {
        float* tb = Ttot + ((size_t)chain * NSEG + g) * 1024 + o * 32;
#pragma unroll
        for (int j = 0; j < 8; ++j)
            ((float4*)tb)[j] = make_float4(p[4 * j], p[4 * j + 1], p[4 * j + 2], p[4 * j + 3]);
    }
}

__global__ __launch_bounds__(64) void scan_pass2a(const float* __restrict__ Ttot,
                                                  float* __restrict__ Eexc,
                                                  float* __restrict__ Utot) {
    int lane = threadIdx.x & 63;
    int o = lane & 31;
    int grp = blockIdx.x;
    int chain = grp >> 3, k = grp & 7;
    float e[32];
#pragma unroll
    for (int q = 0; q < 32; ++q) e[q] = (q == o) ? 1.0f : 0.0f;
    for (int i = 0; i < GRPL; ++i) {
        int g = k * GRPL + i;
        if (lane < 32) {
            float* eb = Eexc + ((size_t)chain * NSEG + g) * 1024 + o * 32;
#pragma unroll
            for (int j = 0; j < 8; ++j)
                ((float4*)eb)[j] = make_float4(e[4 * j], e[4 * j + 1], e[4 * j + 2], e[4 * j + 3]);
        }
        row_matmul(e, Ttot + ((size_t)chain * NSEG + g) * 1024);
    }
    if (lane < 32) {
        float* ub = Utot + ((size_t)chain * NGRP + k) * 1024 + o * 32;
#pragma unroll
        for (int j = 0; j < 8; ++j)
            ((float4*)ub)[j] = make_float4(e[4 * j], e[4 * j + 1], e[4 * j + 2], e[4 * j + 3]);
    }
}

__global__ __launch_bounds__(64) void scan_pass2b(const float* __restrict__ Utot,
                                                  float* __restrict__ Wkp) {
    int lane = threadIdx.x & 63;
    int o = lane & 31;
    int chain = blockIdx.x;
    float w[32];
#pragma unroll
    for (int q = 0; q < 32; ++q) w[q] = (q == o) ? 1.0f : 0.0f;
    for (int k = 0; k < NGRP; ++k) {
        if (lane < 32) {
            float* wb = Wkp + ((size_t)chain * NGRP + k) * 1024 + o * 32;
#pragma unroll
            for (int j = 0; j < 8; ++j)
                ((float4*)wb)[j] = make_float4(w[4 * j], w[4 * j + 1], w[4 * j + 2], w[4 * j + 3]);
        }
        row_matmul(w, Utot + ((size_t)chain * NGRP + k) * 1024);
    }
}

__global__ __launch_bounds__(256) void scan_pass3(const float* __restrict__ h,
                                                  const float* __restrict__ Wup,
                                                  const float* __restrict__ Wdn,
                                                  const float* __restrict__ Eexc,
                                                  const float* __restrict__ Wkp,
                                                  bf16* __restrict__ down,
                                                  float* __restrict__ state_out) {
    int wv = __builtin_amdgcn_readfirstlane((int)(threadIdx.x >> 6));
    int lane = threadIdx.x & 63;
    int o = lane & 31;
    int seg = blockIdx.x * 4 + wv;
    int chain = seg >> 6;
    int g = seg & 63;
    int b = chain >> 4, head = chain & 15;
    int k = g >> 3;

    float wq[64];
#pragma unroll
    for (int j = 0; j < 16; ++j) ((float4*)wq)[j] = ((const float4*)Wup)[j];
    float wd[64];
#pragma unroll
    for (int j = 0; j < 16; ++j) ((float4*)wd)[j] = ((const float4*)Wdn)[j];

    float G00 = 0.f, G01 = 0.f, G10 = 0.f, G11 = 0.f;
#pragma unroll
    for (int q = 0; q < 32; ++q) {
        G00 = fmaf(wq[2 * q + 0], wd[q], G00);
        G01 = fmaf(wq[2 * q + 0], wd[32 + q], G01);
        G10 = fmaf(wq[2 * q + 1], wd[q], G10);
        G11 = fmaf(wq[2 * q + 1], wd[32 + q], G11);
    }

    float wrow[32];
    const float* wb = Wkp + ((size_t)chain * NGRP + k) * 1024 + o * 32;
#pragma unroll
    for (int j = 0; j < 8; ++j) ((float4*)wrow)[j] = ((const float4*)wb)[j];
    const float* Eb = Eexc + ((size_t)chain * NSEG + g) * 1024;
    float p[32];
#pragma unroll
    for (int q = 0; q < 32; ++q) p[q] = 0.f;
#pragma unroll
    for (int kk = 0; kk < 32; ++kk) {
        float wkk = wrow[kk];
        const float4* er = (const float4*)(Eb + kk * 32);
#pragma unroll
        for (int j = 0; j < 8; ++j) {
            float4 ev = er[j];
            p[4 * j + 0] = fmaf(wkk, ev.x, p[4 * j + 0]);
            p[4 * j + 1] = fmaf(wkk, ev.y, p[4 * j + 1]);
            p[4 * j + 2] = fmaf(wkk, ev.z, p[4 * j + 2]);
            p[4 * j + 3] = fmaf(wkk, ev.w, p[4 * j + 3]);
        }
    }

    float d0 = 0.f, d1 = 0.f;
#pragma unroll
    for (int q = 0; q < 32; ++q) {
        d0 = fmaf(p[q], wd[q], d0);
        d1 = fmaf(p[q], wd[32 + q], d1);
    }

    const float* hb = h + ((size_t)b * Ss + (size_t)g * SEGL) * Ee + head * 64;
    bf16* db = down + ((size_t)b * Ss + (size_t)g * SEGL) * Ee + head * 64 + o * 2;
    float* sb = state_out + ((size_t)g * SEGL * Hh + head) * 1024 + o * 32;

    for (int st = 0; st < SEGL; ++st) {
        float y0, y1;
        rank2_step(hb + (size_t)st * Ee, wq, p, y0, y1);
        d0 = fmaf(y0, G00, fmaf(y1, G10, d0));
        d1 = fmaf(y0, G01, fmaf(y1, G11, d1));
        if (lane < 32) {
            __hip_bfloat162 dv;
            dv.x = __float2bfloat16(d0);
            dv.y = __float2bfloat16(d1);
            *(__hip_bfloat162*)(db + (size_t)st * Ee) = dv;
            if (b == Bb - 1) {
                float* sp = sb + (size_t)st * (Hh * 1024);
#pragma unroll
                for (int j = 0; j < 8; ++j)
                    ((float4*)sp)[j] = make_float4(p[4 * j], p[4 * j + 1], p[4 * j + 2], p[4 * j + 3]);
            }
        }
    }
}

// ================= bf16 MFMA GEMM: C = A[M,K] @ W[N,K]^T =================
// 128x128 tile, BK=32, 8 waves (512 thr) each owning 64x32 output,
// double-buffered LDS prefetch-under-compute, XCD-chunked + 8x8-supertile order.
// Per-wave staging footprint: 64 lanes x 16B = 512 shorts -> LDS base w*512 (R6 bug was w*1024).
__device__ __forceinline__ void load_lds16(const bf16* g, short* l) {
    __builtin_amdgcn_global_load_lds((const __attribute__((address_space(1))) unsigned int*)g,
                                     (__attribute__((address_space(3))) unsigned int*)l,
                                     16, 0, 0);
}

template <bool GELU, bool RESID, bool BF16OUT>
__global__ __launch_bounds__(512) void mgemm(const bf16* __restrict__ A,
                                             const bf16* __restrict__ Wt,
                                             const float* __restrict__ res,
                                             float* __restrict__ Cf,
                                             bf16* __restrict__ Cb,
                                             int M, int N, int K) {
    __shared__ __align__(16) short As[2][128 * 32];
    __shared__ __align__(16) short Bs[2][128 * 32];
    int tid = threadIdx.x;
    int w = __builtin_amdgcn_readfirstlane(tid >> 6);
    int l = tid & 63;

    // block remap: XCD chunk + 8x8 supertiles (all grids here have nbm%8==0, nbn%8==0)
    int nbm = M >> 7, nbn = N >> 7;
    int nwg = nbm * nbn;
    int cpx = nwg >> 3;
    int v = ((int)blockIdx.x & 7) * cpx + ((int)blockIdx.x >> 3);
    int sq = v >> 6, rem = v & 63;
    int sqPerRow = nbn >> 3;
    int bm = (sq / sqPerRow) * 8 + (rem >> 3);
    int bn = (sq % sqPerRow) * 8 + (rem & 7);

    int wr = w >> 2, wc = w & 3;           // 2 x 4 wave grid; wave tile 64(M) x 32(N)

    // staging: thread tid covers 16B at flat short idx tid*8 of the [128][32] tile
    // row = tid>>2, col = (tid&3)*8; LDS dest = wave base w*512 + lane*8 (HW adds lane*16B)
    int srow = tid >> 2, scol = (tid & 3) * 8;
    const bf16* ga = A + (size_t)(bm * 128 + srow) * K + scol;
    const bf16* gb = Wt + (size_t)(bn * 128 + srow) * K + scol;

    f32x4 acc[4][2];
#pragma unroll
    for (int m = 0; m < 4; ++m)
#pragma unroll
        for (int n = 0; n < 2; ++n) acc[m][n] = (f32x4){0.f, 0.f, 0.f, 0.f};

    int lr = l & 15, lk = (l >> 4) * 8;
    const int NT = K >> 5;

    // prologue: stage tile 0 into buffer 0
    load_lds16(ga, &As[0][w * 512]);
    load_lds16(gb, &Bs[0][w * 512]);
    ga += 32; gb += 32;
    __syncthreads();                      // implicit vmcnt(0): tile 0 landed

    int cur = 0;
    for (int t = 0; t < NT; ++t) {
        if (t + 1 < NT) {                 // issue next tile's loads before compute
            int nx = cur ^ 1;
            load_lds16(ga, &As[nx][w * 512]);
            load_lds16(gb, &Bs[nx][w * 512]);
            ga += 32; gb += 32;
        }
        short8 af[4], bfr[2];
#pragma unroll
        for (int m = 0; m < 4; ++m)
            af[m] = *(const short8*)&As[cur][(wr * 64 + m * 16 + lr) * 32 + lk];
#pragma unroll
        for (int n = 0; n < 2; ++n)
            bfr[n] = *(const short8*)&Bs[cur][(wc * 32 + n * 16 + lr) * 32 + lk];
#pragma unroll
        for (int m = 0; m < 4; ++m)
#pragma unroll
            for (int n = 0; n < 2; ++n)
                acc[m][n] = __builtin_amdgcn_mfma_f32_16x16x32_bf16(af[m], bfr[n], acc[m][n], 0, 0, 0);
        if (t + 1 < NT) {
            __syncthreads();              // drains prefetch; all waves past reads of As[cur]
            cur ^= 1;
        }
    }

#pragma unroll
    for (int m = 0; m < 4; ++m) {
#pragma unroll
        for (int n = 0; n < 2; ++n) {
            int gr0 = bm * 128 + wr * 64 + m * 16 + (l >> 4) * 4;
            int gc = bn * 128 + wc * 32 + n * 16 + (l & 15);
#pragma unroll
            for (int j = 0; j < 4; ++j) {
                float v2 = acc[m][n][j];
                if (GELU) v2 = 0.5f * v2 * (1.0f + erff(v2 * 0.70710678118654752f));
                if (RESID) v2 += res[(size_t)(gr0 + j) * N + gc];
                if (BF16OUT) Cb[(size_t)(gr0 + j) * N + gc] = __float2bfloat16(v2);
                else Cf[(size_t)(gr0 + j) * N + gc] = v2;
            }
        }
    }
}

extern "C" void kernel_launch(void* const* d_in, const int* in_sizes, int n_in,
                              void* d_out, int out_size, void* d_ws, size_t ws_size,
                              hipStream_t stream) {
    const float* act    = (const float*)d_in[0];
    const float* W_up   = (const float*)d_in[1];
    const float* W_down = (const float*)d_in[2];
    const float* W_mru  = (const float*)d_in[3];
    const float* g_ln1  = (const float*)d_in[4];
    const float* g_ln2  = (const float*)d_in[5];
    const float* W_mlp1 = (const float*)d_in[6];
    const float* W_mlp2 = (const float*)d_in[7];

    float* out_x     = (float*)d_out;
    float* out_state = (float*)d_out + (size_t)Bb * Ss * Ee;

    float* wsf = (float*)d_ws;
    const size_t Mfl = 1024 * 1024;
    float* h        = wsf;                          // [0,4M) fp32 LN1 out
    bf16*  down_bf  = (bf16*)(wsf + 4 * Mfl);       // [4M,6M) 4M bf16
    bf16*  y_bf     = (bf16*)(wsf + 6 * Mfl);       // [6M,8M) 4M bf16
    bf16*  t1_bf    = (bf16*)(wsf + 8 * Mfl);       // [8M,16M) 16M bf16
    // scan scratch overlaps t1 region (dead before t1 written)
    float* Ttot = wsf + 8 * Mfl;                    // 2M floats
    float* Eexc = wsf + 10 * Mfl;                   // 2M floats
    float* Utot = wsf + 12 * Mfl;                   // 256K floats
    float* Wkp  = wsf + 12 * Mfl + 512 * 1024;      // 256K floats
    bf16*  Wmru_bf  = (bf16*)(wsf + 16 * Mfl);      // 1M bf16
    bf16*  Wmlp1_bf = (bf16*)(wsf + 17 * Mfl);      // 4M bf16
    bf16*  Wmlp2_bf = (bf16*)(wsf + 19 * Mfl);      // 4M bf16

    const int MT = Bb * Ss;   // 4096

    f2bf_kernel<<<1024, 256, 0, stream>>>(W_mru, Wmru_bf, (1024 * 1024) / 4);
    f2bf_kernel<<<4096, 256, 0, stream>>>(W_mlp1, Wmlp1_bf, (4 * 1024 * 1024) / 4);
    f2bf_kernel<<<4096, 256, 0, stream>>>(W_mlp2, Wmlp2_bf, (4 * 1024 * 1024) / 4);

    ln_kernel<float><<<MT, 256, 0, stream>>>(act, g_ln1, h);
    scan_pass1<<<512, 256, 0, stream>>>(h, W_up, Ttot);
    scan_pass2a<<<256, 64, 0, stream>>>(Ttot, Eexc, Utot);
    scan_pass2b<<<32, 64, 0, stream>>>(Utot, Wkp);
    scan_pass3<<<512, 256, 0, stream>>>(h, W_up, W_down, Eexc, Wkp, down_bf, out_state);

    {   // x1 = act + down @ W_mru^T
        mgemm<false, true, false><<<(MT / 128) * (Ee / 128), 512, 0, stream>>>(
            down_bf, Wmru_bf, act, out_x, nullptr, MT, Ee, Ee);
    }
    ln_kernel<bf16><<<MT, 256, 0, stream>>>(out_x, g_ln2, y_bf);
    {   // t1 = gelu(y @ W_mlp1^T)  (bf16 out)
        mgemm<true, false, true><<<(MT / 128) * (4 * Ee / 128), 512, 0, stream>>>(
            y_bf, Wmlp1_bf, nullptr, nullptr, t1_bf, MT, 4 * Ee, Ee);
    }
    {   // out_x = x1 + t1 @ W_mlp2^T
        mgemm<false, true, false><<<(MT / 128) * (Ee / 128), 512, 0, stream>>>(
            t1_bf, Wmlp2_bf, out_x, out_x, nullptr, MT, Ee, 4 * Ee);
    }
}